// Round 14
// baseline (756.842 us; speedup 1.0000x reference)
//
#include <hip/hip_runtime.h>

typedef _Float16 f16;
typedef _Float16 f16x4 __attribute__((ext_vector_type(4)));
typedef _Float16 f16x8 __attribute__((ext_vector_type(8)));
typedef float    f32x4 __attribute__((ext_vector_type(4)));
typedef int      i32x4 __attribute__((ext_vector_type(4)));
typedef unsigned int u32;

#define MFMA16(a,b,c) __builtin_amdgcn_mfma_f32_16x16x32_f16((a),(b),(c),0,0,0)
#define MFMAI8(a,b,c) __builtin_amdgcn_mfma_i32_16x16x64_i8((a),(b),(c),0,0,0)

typedef __attribute__((address_space(1))) const u32 gu32;
typedef __attribute__((address_space(3))) u32 lu32;

static __device__ __forceinline__ float frcp(float x){ float r; asm("v_rcp_f32 %0, %1" : "=v"(r) : "v"(x)); return r; }
static __device__ __forceinline__ float frsq(float x){ float r; asm("v_rsq_f32 %0, %1" : "=v"(r) : "v"(x)); return r; }
static __device__ __forceinline__ float sigm(float x){ return frcp(1.0f + __expf(-x)); }
static __device__ __forceinline__ float tanh_(float x){ return 1.0f - 2.0f*frcp(1.0f + __expf(2.0f*x)); }

static __device__ __forceinline__ void bar_lgkm(){
  asm volatile("s_waitcnt lgkmcnt(0)" ::: "memory");
  __builtin_amdgcn_s_barrier();
  asm volatile("" ::: "memory");
}
static __device__ __forceinline__ void bar_plain(){
  asm volatile("" ::: "memory");
  __builtin_amdgcn_s_barrier();
  asm volatile("" ::: "memory");
}
// producer-done flag wait: relaxed spin, then one acquire (L1/L2 inv)
static __device__ __forceinline__ void waitflag(u32* f){
  if (__hip_atomic_load(f, __ATOMIC_ACQUIRE, __HIP_MEMORY_SCOPE_AGENT)) return;
  while (__hip_atomic_load(f, __ATOMIC_RELAXED, __HIP_MEMORY_SCOPE_AGENT) == 0)
    __builtin_amdgcn_s_sleep(8);
  (void)__hip_atomic_load(f, __ATOMIC_ACQUIRE, __HIP_MEMORY_SCOPE_AGENT);
}

// ---------------- workspace layout (bytes) ----------------
static constexpr size_t OFF_WSE_P  = 0;
static constexpr size_t OFF_WSD_P  = OFF_WSE_P  + (size_t)8192*256*2;
static constexpr size_t OFF_WIHE_P = OFF_WSD_P  + (size_t)8192*256*2;
static constexpr size_t OFF_WIHD_P = OFF_WIHE_P + (size_t)256*1024*2;
static constexpr size_t OFF_WHHE_P = OFF_WIHD_P + (size_t)256*1024*2;    // i8
static constexpr size_t OFF_WHHD_P = OFF_WHHE_P + (size_t)256*1024;      // i8
static constexpr size_t OFF_W3E    = OFF_WHHD_P + (size_t)256*1024;
static constexpr size_t OFF_W3D    = OFF_W3E   + (size_t)3*1024*4;
static constexpr size_t OFF_W2WO   = OFF_W3D   + (size_t)3*1024*4;
static constexpr size_t OFF_BIASE  = OFF_W2WO  + (size_t)256*3*4;
static constexpr size_t OFF_BIASD  = OFF_BIASE + (size_t)1024*4;
static constexpr size_t OFF_B2WO   = OFF_BIASD + (size_t)1024*4;
static constexpr size_t OFF_PREGE  = OFF_B2WO  + 256;
static constexpr size_t OFF_PREGD  = OFF_PREGE + (size_t)5120*1024*2;
static constexpr size_t OFF_FLAGS  = OFF_PREGD + (size_t)25600*1024*2;   // 240 u32

// ================= prep: pack weights + small folds + zero flags ============
__global__ __launch_bounds__(256) void k_prep(
    const float* __restrict__ Wse, const float* __restrict__ Wsd,
    const float* __restrict__ Wih_e, const float* __restrict__ Wih_d,
    const float* __restrict__ Whh_e, const float* __restrict__ Whh_d,
    f16* pWse, f16* pWsd, f16* pWih_e, f16* pWih_d,
    signed char* pWhh_e, signed char* pWhh_d,
    const float* __restrict__ Wpe, const float* __restrict__ bpe,
    const float* __restrict__ bih_e, const float* __restrict__ bhh_e,
    const float* __restrict__ Wpd, const float* __restrict__ bpd,
    const float* __restrict__ bih_d, const float* __restrict__ bhh_d,
    const float* __restrict__ W2, const float* __restrict__ b2,
    const float* __restrict__ Wo, const float* __restrict__ bo,
    float* W3e, float* W3d, float* biasE, float* biasD, float* W2Wo, float* b2Wo,
    u32* flags)
{
  int blk = blockIdx.x;
  if (blk < 2304) {
    const float* W; f16* o; int N, base;
    if      (blk < 1024) { W=Wse;   o=pWse;   N=256;  base=0; }
    else if (blk < 2048) { W=Wsd;   o=pWsd;   N=256;  base=1024; }
    else if (blk < 2176) { W=Wih_e; o=pWih_e; N=1024; base=2048; }
    else                 { W=Wih_d; o=pWih_d; N=1024; base=2176; }
    int tid = (blk - base)*256 + threadIdx.x;
    int l = tid & 63;
    int nct = N >> 4;
    int ctg = (tid >> 6) % nct;
    int kfg = (tid >> 6) / nct;
    int k0  = kfg*32 + ((l>>4)<<3);
    int col = ctg*16 + (l&15);
    f16x8 v;
#pragma unroll
    for (int i=0;i<8;++i) v[i] = (f16)W[(size_t)(k0+i)*N + col];
    *(f16x8*)(o + (size_t)tid*8) = v;
    return;
  }
  if (blk < 2432) {
    const float* W; signed char* o; int base;
    if (blk < 2368) { W=Whh_e; o=pWhh_e; base=2304; }
    else            { W=Whh_d; o=pWhh_d; base=2368; }
    int tid = (blk - base)*256 + threadIdx.x;
    int l = tid & 63;
    int unit = tid >> 6;                        // [kfg(4)][ctg(64)]
    int kfg = unit >> 6, ctg = unit & 63;
    int k0  = kfg*64 + ((l>>4)<<4);
    int col = ctg*16 + (l&15);
    signed char* dst = o + ((size_t)unit*64 + l)*16;
#pragma unroll
    for (int e=0;e<16;++e) {
      int q = __float2int_rn(W[(size_t)(k0+e)*1024 + col] * 1024.0f);
      q = q > 127 ? 127 : (q < -127 ? -127 : q);
      dst[e] = (signed char)q;
    }
    return;
  }
  int bid = blk - 2432, tid = threadIdx.x;
  if (bid < 4) {
    int j = bid*256 + tid;
    float s0=0,s1=0,s2=0,sb=0;
    for (int m=0;m<256;++m) {
      float wv = Wih_e[(size_t)(256+m)*1024 + j];
      s0 += Wpe[m]*wv; s1 += Wpe[256+m]*wv; s2 += Wpe[512+m]*wv; sb += bpe[m]*wv;
    }
    W3e[j]=s0; W3e[1024+j]=s1; W3e[2048+j]=s2;
    biasE[j] = bih_e[j] + bhh_e[j] + sb;
  } else if (bid < 8) {
    int j = (bid-4)*256 + tid;
    float s0=0,s1=0,s2=0,sb=0;
    for (int m=0;m<256;++m) {
      float wv = Wih_d[(size_t)(256+m)*1024 + j];
      s0 += Wpd[m]*wv; s1 += Wpd[256+m]*wv; s2 += Wpd[512+m]*wv; sb += bpd[m]*wv;
    }
    W3d[j]=s0; W3d[1024+j]=s1; W3d[2048+j]=s2;
    biasD[j] = bih_d[j] + bhh_d[j] + sb;
  } else if (bid == 8) {
    int c = tid;
    float s0=0,s1=0,s2=0;
    for (int m=0;m<256;++m) {
      float wv = W2[(size_t)c*256+m];
      s0 += wv*Wo[m*3+0]; s1 += wv*Wo[m*3+1]; s2 += wv*Wo[m*3+2];
    }
    W2Wo[c*3+0]=s0; W2Wo[c*3+1]=s1; W2Wo[c*3+2]=s2;
  } else if (bid == 9) {
    if (tid < 192) {
      int j = tid >> 6, lane = tid & 63;
      float s = 0.f;
      for (int m=lane;m<256;m+=64) s += b2[m]*Wo[m*3+j];
#pragma unroll
      for (int msk=1;msk<64;msk<<=1) s += __shfl_xor(s, msk);
      if (lane==0) b2Wo[j] = s + bo[j];
    }
  } else {
    if (tid < 240) flags[tid] = 0u;   // per-gemm-tile done flags
  }
}

// ======== merged kernel: blocks [0,64) = RNN, [64,304) = GEMM tiles =========
// GEMM: preg = (A(f32,K=8192)@Ws + bs) @ Wih + bias [+ pos@W3e for enc].
//   128x256 tile, 8 waves (2 row x 4 col), t-major rows; release-flag on done.
// RNN: encoder(5)+decoder(25); int8 Whh streamed via counted-vmcnt LDS FIFO;
//   preg consumption gated by per-tile acquire flags.
__global__ __launch_bounds__(512) void k_main(
    const float* __restrict__ A0, const f16* __restrict__ W0,
    const float* __restrict__ bs0, const f16* __restrict__ Wih0,
    const float* __restrict__ bias0, f16* __restrict__ P0,
    const float* __restrict__ pos0, const float* __restrict__ W3f0,
    const float* __restrict__ A1, const f16* __restrict__ W1,
    const float* __restrict__ bs1, const f16* __restrict__ Wih1,
    const float* __restrict__ bias1, f16* __restrict__ P1,
    const signed char* __restrict__ Whh_e_p, const signed char* __restrict__ Whh_d_p,
    const float* __restrict__ W3d, const float* __restrict__ dec_pos,
    const float* __restrict__ W2Wo, const float* __restrict__ b2Wo,
    u32* flags, float* __restrict__ out)
{
  __shared__ __align__(16) char smem[150208];
  const int tid = threadIdx.x, l = tid & 63, w = tid >> 6;
  const int li = l & 15, hi = l >> 4;
  const int bx = blockIdx.x;

  if (bx >= 64) {
    // ==================== GEMM path ====================
    f16 (*aLDS)[8192] = (f16(*)[8192])smem;       // [2][128*64], 16B-slot ^= row&7
    f16* sLDS = (f16*)(smem + 32768);             // [128*256]
    const int wr = w >> 2, wc = w & 3;
    const int gx = bx - 64;
    const float *Ap,*bs,*bias,*posf,*W3f; const f16 *Wp,*Wih; f16* P; int t,b0,T;
    if (gx < 40) { t=gx>>3; b0=(gx&7)<<7; Ap=A0;Wp=W0;bs=bs0;Wih=Wih0;bias=bias0;P=P0;T=5; posf=pos0; W3f=W3f0; }
    else { int d=gx-40; t=d>>3; b0=(d&7)<<7; Ap=A1;Wp=W1;bs=bs1;Wih=Wih1;bias=bias1;P=P1;T=25; posf=nullptr; W3f=nullptr; }

    f32x4 acc[4][4];
#pragma unroll
    for (int a=0;a<4;++a)
#pragma unroll
      for (int b=0;b<4;++b) acc[a][b] = (f32x4){0.f,0.f,0.f,0.f};

    const int arow = tid >> 2, kseg = tid & 3;    // 128 rows x 4 k-segs
    const float* Arow = Ap + ((size_t)(b0 + arow)*T + t)*8192 + kseg*16;

    float4 fA0,fA1,fA2,fA3, fB0,fB1,fB2,fB3;
#define LOADA_A(ti_) { const float* Aq = Arow + (ti_)*64;                      \
    fA0 = *(const float4*)Aq;     fA1 = *(const float4*)(Aq+4);                \
    fA2 = *(const float4*)(Aq+8); fA3 = *(const float4*)(Aq+12); }
#define LOADA_B(ti_) { const float* Aq = Arow + (ti_)*64;                      \
    fB0 = *(const float4*)Aq;     fB1 = *(const float4*)(Aq+4);                \
    fB2 = *(const float4*)(Aq+8); fB3 = *(const float4*)(Aq+12); }
#define GMFMA(buf_, kfg0_)                                                     \
    _Pragma("unroll")                                                          \
    for (int kf = 0; kf < 2; ++kf) {                                           \
      f16x8 afr[4], bfr[4];                                                    \
      _Pragma("unroll")                                                        \
      for (int rt=0; rt<4; ++rt) {                                             \
        int row = wr*64 + rt*16 + li;                                          \
        afr[rt] = *(f16x8*)&aLDS[buf_][row*64 + (((kf*4) + hi) ^ (row&7))*8];  \
      }                                                                        \
      _Pragma("unroll")                                                        \
      for (int ct=0; ct<4; ++ct) {                                             \
        int ctg = wc*4 + ct;                                                   \
        bfr[ct] = *(const f16x8*)(Wp + ((size_t)(((kfg0_)+kf)*16 + ctg)*64 + l)*8); \
      }                                                                        \
      _Pragma("unroll")                                                        \
      for (int rt=0; rt<4; ++rt)                                               \
        _Pragma("unroll")                                                      \
        for (int ct=0; ct<4; ++ct)                                             \
          acc[rt][ct] = MFMA16(afr[rt], bfr[ct], acc[rt][ct]);                 \
    }
#define GSTEP(F0,F1,F2,F3, RELOAD, buf_, ti_) {                                \
      f16x8 w0, w1;                                                            \
      w0[0]=(f16)F0.x; w0[1]=(f16)F0.y; w0[2]=(f16)F0.z; w0[3]=(f16)F0.w;      \
      w0[4]=(f16)F1.x; w0[5]=(f16)F1.y; w0[6]=(f16)F1.z; w0[7]=(f16)F1.w;      \
      w1[0]=(f16)F2.x; w1[1]=(f16)F2.y; w1[2]=(f16)F2.z; w1[3]=(f16)F2.w;      \
      w1[4]=(f16)F3.x; w1[5]=(f16)F3.y; w1[6]=(f16)F3.z; w1[7]=(f16)F3.w;      \
      bar_plain();                                                             \
      *(f16x8*)&aLDS[buf_][arow*64 + ((kseg*2    ) ^ (arow&7))*8] = w0;        \
      *(f16x8*)&aLDS[buf_][arow*64 + ((kseg*2 + 1) ^ (arow&7))*8] = w1;        \
      { int tn = ((ti_)+2 < 128) ? (ti_)+2 : 127; RELOAD(tn); }                \
      bar_lgkm();                                                              \
      GMFMA(buf_, (ti_)*2)                                                     \
    }

    LOADA_A(0); LOADA_B(1);
    for (int ti = 0; ti < 128; ti += 2) {
      GSTEP(fA0,fA1,fA2,fA3, LOADA_A, 0, ti)
      GSTEP(fB0,fB1,fB2,fB3, LOADA_B, 1, ti+1)
    }
#undef LOADA_A
#undef LOADA_B
#undef GMFMA
#undef GSTEP
    // stage-1 epilogue: sal tile (+bs) -> sLDS, swizzled row-major [128][256]
    bar_plain();
#pragma unroll
    for (int ct=0; ct<4; ++ct) {
      int col = (wc*4 + ct)*16 + li;
      float bv = bs[col];
      int slot = col >> 3;
#pragma unroll
      for (int rt=0; rt<4; ++rt)
#pragma unroll
        for (int i=0;i<4;++i) {
          int row = wr*64 + rt*16 + hi*4 + i;
          sLDS[row*256 + ((slot ^ (row&7))<<3) + (col&7)] = (f16)(acc[rt][ct][i] + bv);
        }
    }
    float pe[4][4][3];
    if (posf) {
#pragma unroll
      for (int rt=0; rt<4; ++rt)
#pragma unroll
        for (int i=0;i<4;++i) {
          int brow = b0 + wr*64 + rt*16 + hi*4 + i;
          const float* pq = posf + ((size_t)brow*T + t)*3;
          pe[rt][i][0]=pq[0]; pe[rt][i][1]=pq[1]; pe[rt][i][2]=pq[2];
        }
    }
    __syncthreads();
    // stage-2: sal(128x256) @ Wih(256x1024), 4 col-chunks of 256
#pragma unroll
    for (int cg=0; cg<4; ++cg) {
      f32x4 a2[4][4];
#pragma unroll
      for (int a=0;a<4;++a)
#pragma unroll
        for (int b=0;b<4;++b) a2[a][b] = (f32x4){0.f,0.f,0.f,0.f};
#pragma unroll
      for (int kfg=0; kfg<8; ++kfg) {
        f16x8 afr[4], bfr[4];
#pragma unroll
        for (int rt=0; rt<4; ++rt) {
          int row = wr*64 + rt*16 + li;
          afr[rt] = *(f16x8*)&sLDS[row*256 + (((kfg*4 + hi) ^ (row&7))<<3)];
        }
#pragma unroll
        for (int ct=0; ct<4; ++ct) {
          int ctg2 = cg*16 + wc*4 + ct;
          bfr[ct] = *(const f16x8*)(Wih + ((size_t)(kfg*64 + ctg2)*64 + l)*8);
        }
#pragma unroll
        for (int rt=0; rt<4; ++rt)
#pragma unroll
          for (int ct=0; ct<4; ++ct)
            a2[rt][ct] = MFMA16(afr[rt], bfr[ct], a2[rt][ct]);
      }
#pragma unroll
      for (int ct=0; ct<4; ++ct) {
        const int ctg2 = cg*16 + wc*4 + ct;
        const float bv = bias[ctg2*16 + li];
        float w30=0.f, w31=0.f, w32=0.f;
        if (posf) { int gc = ctg2*16 + li; w30=W3f[gc]; w31=W3f[1024+gc]; w32=W3f[2048+gc]; }
#pragma unroll
        for (int rt=0; rt<4; ++rt) {
          f16x4 o;
#pragma unroll
          for (int i=0;i<4;++i) {
            float v = a2[rt][ct][i] + bv;
            if (posf) v += pe[rt][i][0]*w30 + pe[rt][i][1]*w31 + pe[rt][i][2]*w32;
            o[i] = (f16)v;
          }
          int bb = (b0>>4) + wr*4 + rt;
          *(f16x4*)(P + ((size_t)(bb*T + t)*64 + ctg2)*256 + l*4) = o;
        }
      }
    }
    __syncthreads();   // all stores retired block-wide
    if (tid == 0)
      __hip_atomic_store(&flags[gx], 1u, __ATOMIC_RELEASE, __HIP_MEMORY_SCOPE_AGENT);
    return;
  }

  // ==================== RNN path ====================
  signed char (*wLDS)[4][4][1024] = (signed char(*)[4][4][1024])smem;   // 128 KB
  signed char (*hBuf)[16*256] = (signed char(*)[16*256])(smem + 131072); // 8 KB
  f16* W3h = (f16*)(smem + 139264);                                      // 6 KB
  float (*dpart)[16][3] = (float(*)[16][3])(smem + 145408);              // 4.7 KB
  const int bblk = bx, rb = bblk*16, g = bblk >> 3;
  const float SC = 1.0f/130048.0f;

  for (int i=tid;i<3072;i+=512) W3h[i] = (f16)W3d[i];
  for (int i=tid; i<25*16*3; i+=512) ((float*)dpart)[i] = 0.f;

  float c_st[2][4];
#pragma unroll
  for (int j=0;j<2;++j)
#pragma unroll
    for (int i=0;i<4;++i) c_st[j][i]=0.f;

#define VMW(n) { asm volatile("s_waitcnt vmcnt(" #n ")" ::: "memory");        \
                 __builtin_amdgcn_sched_barrier(0); }
#define STAGE(WP, kf, h, s)                                                   \
  _Pragma("unroll") for (int f=0; f<4; ++f) {                                 \
    int ctg = ((h)*2 + (f>>1))*16 + w*2 + (f&1);                              \
    const signed char* gp = (WP) + ((size_t)((kf)*64 + ctg)*64 + l)*16;       \
    __builtin_amdgcn_global_load_lds((gu32*)gp, (lu32*)&wLDS[w][s][f][0], 16, 0, 0); \
  }
#define AH(ah, hB, kf) ah = *(i32x4*)&(hB)[li*256 + ((((kf)*4)+hi) ^ (li&7))*16];
#define MFMA4(s, h, ah)                                                       \
  _Pragma("unroll") for (int f=0; f<4; ++f) {                                 \
    i32x4 b = *(i32x4*)&wLDS[w][s][f][l*16];                                  \
    acc[(h)*2 + (f>>1)][f&1] = MFMAI8(ah, b, acc[(h)*2 + (f>>1)][f&1]); }
// 8-point stream; safe for entry queue of 0 (post-acquire drain) or 12.
// Tail waits VMW(16): guarantee p6 (younger = p7+pv8+p0'=16), p7 (pv8+p0'+p1'=16).
#define KFSTREAM8(hB, WP, WPn, PVB, PVT) {                                    \
  i32x4 ah;                                                                   \
  VMW(8) AH(ah, hB, 0) MFMA4(0, 0, ah) STAGE(WP, 1, 1, 3)                     \
  VMW(8)               MFMA4(1, 1, ah) STAGE(WP, 2, 0, 0)                     \
  VMW(8) AH(ah, hB, 1) MFMA4(2, 0, ah) STAGE(WP, 2, 1, 1)                     \
  VMW(8)               MFMA4(3, 1, ah) STAGE(WP, 3, 0, 2)                     \
  VMW(8) AH(ah, hB, 2) MFMA4(0, 0, ah) STAGE(WP, 3, 1, 3)                     \
  VMW(8)               MFMA4(1, 1, ah) LOADPV(pvB, PVB, PVT) STAGE(WPn, 0, 0, 0) \
  VMW(16) AH(ah, hB, 3) MFMA4(2, 0, ah) STAGE(WPn, 0, 1, 1)                   \
  VMW(16)               MFMA4(3, 1, ah) STAGE(WPn, 1, 0, 2)                   \
  }
#define LOADPV(dst, base, t_)                                                 \
  _Pragma("unroll")                                                           \
  for (int q=0;q<4;++q)                                                       \
    _Pragma("unroll")                                                         \
    for (int j=0;j<2;++j)                                                     \
      dst[q][j] = *(const f16x4*)((base) + ((size_t)(t_)*16384 + (size_t)(q*16 + w*2 + j)*256 + l*4));
#define COPYPV()                                                              \
  _Pragma("unroll")                                                           \
  for (int q=0;q<4;++q)                                                       \
    _Pragma("unroll")                                                         \
    for (int j=0;j<2;++j) pvA[q][j] = pvB[q][j];
#define ACCZERO()                                                             \
  i32x4 acc[4][2];                                                            \
  _Pragma("unroll")                                                           \
  for (int q=0;q<4;++q)                                                       \
    _Pragma("unroll")                                                         \
    for (int j=0;j<2;++j) acc[q][j] = (i32x4){0,0,0,0};
#define HWRITE(hB, r, hc, hval)                                               \
  (hB)[(r)*256 + ((((hc)>>4) ^ ((r)&7))<<4) + ((hc)&15)] =                    \
      (signed char)__float2int_rn((hval)*127.0f);

  const f16* prE = P0 + (size_t)bblk*5*16384;
  const f16* prD = P1 + (size_t)bblk*25*16384;
  f16x4 pvA[4][2], pvB[4][2];

  __syncthreads();                 // W3h + dpart init visible (once)
  STAGE(Whh_e_p,0,0,0) STAGE(Whh_e_p,0,1,1) STAGE(Whh_e_p,1,0,2)   // p0,p1,p2
  waitflag(&flags[0*8 + g]);       // enc t=0 preg ready
  LOADPV(pvA, prE, 0)

  // ---------------- encoder (gate = pv + acc: bias+pos pre-folded) ---------
  for (int t=0;t<5;++t) {
    if (t < 4) waitflag(&flags[(t+1)*8 + g]);
    else       waitflag(&flags[40 + 0*8 + g]);
    ACCZERO()
    if (t > 0) {
      if (t < 4) { KFSTREAM8(hBuf[(t-1)&1], Whh_e_p, Whh_e_p, prE, t+1) }
      else       { KFSTREAM8(hBuf[(t-1)&1], Whh_e_p, Whh_d_p, prD, 0)   }
    }
#pragma unroll
    for (int i=0;i<4;++i) {
      int r = hi*4 + i;
#pragma unroll
      for (int j=0;j<2;++j) {
        int hc = w*32 + j*16 + li;
        float gq[4];
#pragma unroll
        for (int q=0;q<4;++q)
          gq[q] = (float)pvA[q][j][i] + (float)acc[q][j][i]*SC;
        float cn = sigm(gq[1])*c_st[j][i] + sigm(gq[0])*tanh_(gq[2]);
        c_st[j][i] = cn;
        float h = sigm(gq[3])*tanh_(cn);
        HWRITE(hBuf[t&1], r, hc, h)
      }
    }
    if (t == 0) LOADPV(pvB, prE, 1)
    COPYPV()
    bar_lgkm();                    // h[t] visible; stages stay in flight
  }

  // ---------------- decoder constants ----------------
  float w2r[2][3];
#pragma unroll
  for (int j=0;j<2;++j) {
    int hc = w*32 + j*16 + li;
    w2r[j][0]=W2Wo[hc*3+0]; w2r[j][1]=W2Wo[hc*3+1]; w2r[j][2]=W2Wo[hc*3+2];
  }
  const float b2w0 = b2Wo[0], b2w1 = b2Wo[1], b2w2 = b2Wo[2];
  float pp[4][3];
#pragma unroll
  for (int i=0;i<4;++i) {
    int r = rb + hi*4 + i;
    pp[i][0]=dec_pos[r*3+0]; pp[i][1]=dec_pos[r*3+1]; pp[i][2]=dec_pos[r*3+2];
  }

  // ---------------- decoder (1 lgkm-barrier/step) ----------------
  for (int t=0;t<25;++t) {
    if (t+1 < 25) waitflag(&flags[40 + (t+1)*8 + g]);
    ACCZERO()
    if (t+1 < 25) { KFSTREAM8(hBuf[t&1], Whh_d_p, Whh_d_p, prD, t+1) }
    else          { KFSTREAM8(hBuf[t&1], Whh_d_p, Whh_d_p, prD, 24)  }
    float w3v[2][4][3];
#pragma unroll
    for (int j=0;j<2;++j)
#pragma unroll
      for (int q=0;q<4;++q) {
        int gc = q*256 + w*32 + j*16 + li;
        w3v[j][q][0] = (float)W3h[gc];
        w3v[j][q][1] = (float)W3h[1024+gc];
        w3v[j][q][2] = (float)W3h[2048+gc];
      }
    float dpar[4][3];
#pragma unroll
    for (int i=0;i<4;++i){ dpar[i][0]=0.f; dpar[i][1]=0.f; dpar[i][2]=0.f; }
#pragma unroll
    for (int i=0;i<4;++i) {
      int r = hi*4 + i;
#pragma unroll
      for (int j=0;j<2;++j) {
        int hc = w*32 + j*16 + li;
        float gq[4];
#pragma unroll
        for (int q=0;q<4;++q)
          gq[q] = (float)pvA[q][j][i] + (float)acc[q][j][i]*SC
                + pp[i][0]*w3v[j][q][0] + pp[i][1]*w3v[j][q][1] + pp[i][2]*w3v[j][q][2];
        float cn = sigm(gq[1])*c_st[j][i] + sigm(gq[0])*tanh_(gq[2]);
        c_st[j][i] = cn;
        float h = sigm(gq[3])*tanh_(cn);
        HWRITE(hBuf[(t+1)&1], r, hc, h)
        dpar[i][0] += h*w2r[j][0];
        dpar[i][1] += h*w2r[j][1];
        dpar[i][2] += h*w2r[j][2];
      }
    }
#pragma unroll
    for (int m=1;m<16;m<<=1)
#pragma unroll
      for (int i=0;i<4;++i) {
        dpar[i][0] += __shfl_xor(dpar[i][0], m);
        dpar[i][1] += __shfl_xor(dpar[i][1], m);
        dpar[i][2] += __shfl_xor(dpar[i][2], m);
      }
    if (li==0) {
#pragma unroll
      for (int i=0;i<4;++i) {
        int r = hi*4 + i;
        atomicAdd(&dpart[t][r][0], dpar[i][0]);
        atomicAdd(&dpart[t][r][1], dpar[i][1]);
        atomicAdd(&dpart[t][r][2], dpar[i][2]);
      }
    }
    COPYPV()
    bar_lgkm();                    // h[t+1] + dpart[t] visible; stages alive
#pragma unroll
    for (int i=0;i<4;++i) {
      int r = hi*4 + i;
      float p0 = pp[i][0] + b2w0 + dpart[t][r][0];
      float p1 = pp[i][1] + b2w1 + dpart[t][r][1];
      float p2 = pp[i][2] + b2w2 + dpart[t][r][2];
      float inv = frsq(p0*p0+p1*p1+p2*p2);
      pp[i][0]=p0*inv; pp[i][1]=p1*inv; pp[i][2]=p2*inv;
      if (w==0 && li==0) {
        float* o = out + (size_t)(rb+r)*75 + t*3;
        o[0]=pp[i][0]; o[1]=pp[i][1]; o[2]=pp[i][2];
      }
    }
  }
#undef VMW
#undef STAGE
#undef AH
#undef MFMA4
#undef KFSTREAM8
#undef LOADPV
#undef COPYPV
#undef ACCZERO
#undef HWRITE
}

// ================= launch =================
extern "C" void kernel_launch(void* const* d_in, const int* in_sizes, int n_in,
                              void* d_out, int out_size, void* d_ws, size_t ws_size,
                              hipStream_t stream)
{
  const float* enc_pos = (const float*)d_in[0];
  const float* enc_sal = (const float*)d_in[1];
  const float* dec_pos = (const float*)d_in[2];
  const float* dec_sal = (const float*)d_in[3];
  const float* Wpe  = (const float*)d_in[4];
  const float* bpe  = (const float*)d_in[5];
  const float* Wse  = (const float*)d_in[6];
  const float* bse  = (const float*)d_in[7];
  const float* Wih_e= (const float*)d_in[8];
  const float* Whh_e= (const float*)d_in[9];
  const float* bih_e= (const float*)d_in[10];
  const float* bhh_e= (const float*)d_in[11];
  const float* Wih_d= (const float*)d_in[12];
  const float* Whh_d= (const float*)d_in[13];
  const float* bih_d= (const float*)d_in[14];
  const float* bhh_d= (const float*)d_in[15];
  const float* Wpd  = (const float*)d_in[16];
  const float* bpd  = (const float*)d_in[17];
  const float* Wsd  = (const float*)d_in[18];
  const float* bsd  = (const float*)d_in[19];
  const float* W2   = (const float*)d_in[20];
  const float* b2   = (const float*)d_in[21];
  const float* Wo   = (const float*)d_in[22];
  const float* bo   = (const float*)d_in[23];

  char* ws = (char*)d_ws;
  f16* pWse   = (f16*)(ws + OFF_WSE_P);
  f16* pWsd   = (f16*)(ws + OFF_WSD_P);
  f16* pWih_e = (f16*)(ws + OFF_WIHE_P);
  f16* pWih_d = (f16*)(ws + OFF_WIHD_P);
  signed char* pWhh_e = (signed char*)(ws + OFF_WHHE_P);
  signed char* pWhh_d = (signed char*)(ws + OFF_WHHD_P);
  float* W3e  = (float*)(ws + OFF_W3E);
  float* W3d  = (float*)(ws + OFF_W3D);
  float* W2WoP= (float*)(ws + OFF_W2WO);
  float* biasE= (float*)(ws + OFF_BIASE);
  float* biasD= (float*)(ws + OFF_BIASD);
  float* b2WoP= (float*)(ws + OFF_B2WO);
  f16* pregE  = (f16*)(ws + OFF_PREGE);
  f16* pregD  = (f16*)(ws + OFF_PREGD);
  u32* flags  = (u32*)(ws + OFF_FLAGS);
  float* out  = (float*)d_out;

  hipLaunchKernelGGL(k_prep, dim3(2443), dim3(256), 0, stream,
                     Wse, Wsd, Wih_e, Wih_d, Whh_e, Whh_d,
                     pWse, pWsd, pWih_e, pWih_d, pWhh_e, pWhh_d,
                     Wpe, bpe, bih_e, bhh_e, Wpd, bpd, bih_d, bhh_d,
                     W2, b2, Wo, bo,
                     W3e, W3d, biasE, biasD, W2WoP, b2WoP, flags);
  // merged: rnn blocks [0,64) + gemm tiles [64,304)
  hipLaunchKernelGGL(k_main, dim3(304), dim3(512), 0, stream,
                     enc_sal, pWse, bse, pWih_e, biasE, pregE, enc_pos, W3e,
                     dec_sal, pWsd, bsd, pWih_d, biasD, pregD,
                     pWhh_e, pWhh_d, W3d, dec_pos, W2WoP, b2WoP,
                     flags, out);
}

// Round 15
// 522.759 us; speedup vs baseline: 1.4478x; 1.4478x over previous
//
#include <hip/hip_runtime.h>

typedef _Float16 f16;
typedef _Float16 f16x4 __attribute__((ext_vector_type(4)));
typedef _Float16 f16x8 __attribute__((ext_vector_type(8)));
typedef float    f32x4 __attribute__((ext_vector_type(4)));
typedef int      i32x4 __attribute__((ext_vector_type(4)));
typedef unsigned int u32;

#define MFMA16(a,b,c) __builtin_amdgcn_mfma_f32_16x16x32_f16((a),(b),(c),0,0,0)
#define MFMAI8(a,b,c) __builtin_amdgcn_mfma_i32_16x16x64_i8((a),(b),(c),0,0,0)

typedef __attribute__((address_space(1))) const u32 gu32;
typedef __attribute__((address_space(3))) u32 lu32;

static __device__ __forceinline__ float frcp(float x){ float r; asm("v_rcp_f32 %0, %1" : "=v"(r) : "v"(x)); return r; }
static __device__ __forceinline__ float frsq(float x){ float r; asm("v_rsq_f32 %0, %1" : "=v"(r) : "v"(x)); return r; }
static __device__ __forceinline__ float sigm(float x){ return frcp(1.0f + __expf(-x)); }
static __device__ __forceinline__ float tanh_(float x){ return 1.0f - 2.0f*frcp(1.0f + __expf(2.0f*x)); }

static __device__ __forceinline__ void bar_lgkm(){
  asm volatile("s_waitcnt lgkmcnt(0)" ::: "memory");
  __builtin_amdgcn_s_barrier();
  asm volatile("" ::: "memory");
}
static __device__ __forceinline__ void bar_plain(){
  asm volatile("" ::: "memory");
  __builtin_amdgcn_s_barrier();
  asm volatile("" ::: "memory");
}

// ---------------- workspace layout (bytes) ----------------
static constexpr size_t OFF_WSE_P  = 0;
static constexpr size_t OFF_WSD_P  = OFF_WSE_P  + (size_t)8192*256*2;
static constexpr size_t OFF_WIHE_P = OFF_WSD_P  + (size_t)8192*256*2;
static constexpr size_t OFF_WIHD_P = OFF_WIHE_P + (size_t)256*1024*2;
static constexpr size_t OFF_WHHE_P = OFF_WIHD_P + (size_t)256*1024*2;    // i8
static constexpr size_t OFF_WHHD_P = OFF_WHHE_P + (size_t)256*1024;      // i8
static constexpr size_t OFF_W3E    = OFF_WHHD_P + (size_t)256*1024;
static constexpr size_t OFF_W3D    = OFF_W3E   + (size_t)3*1024*4;
static constexpr size_t OFF_W2WO   = OFF_W3D   + (size_t)3*1024*4;
static constexpr size_t OFF_BIASE  = OFF_W2WO  + (size_t)256*3*4;
static constexpr size_t OFF_BIASD  = OFF_BIASE + (size_t)1024*4;
static constexpr size_t OFF_B2WO   = OFF_BIASD + (size_t)1024*4;
static constexpr size_t OFF_PREGE  = OFF_B2WO  + 256;
static constexpr size_t OFF_PREGD  = OFF_PREGE + (size_t)5120*1024*2;
static constexpr size_t OFF_END    = OFF_PREGD + (size_t)25600*1024*2;

// ================= prep: pack weights + small folds (R13 verbatim) =========
__global__ __launch_bounds__(256) void k_prep(
    const float* __restrict__ Wse, const float* __restrict__ Wsd,
    const float* __restrict__ Wih_e, const float* __restrict__ Wih_d,
    const float* __restrict__ Whh_e, const float* __restrict__ Whh_d,
    f16* pWse, f16* pWsd, f16* pWih_e, f16* pWih_d,
    signed char* pWhh_e, signed char* pWhh_d,
    const float* __restrict__ Wpe, const float* __restrict__ bpe,
    const float* __restrict__ bih_e, const float* __restrict__ bhh_e,
    const float* __restrict__ Wpd, const float* __restrict__ bpd,
    const float* __restrict__ bih_d, const float* __restrict__ bhh_d,
    const float* __restrict__ W2, const float* __restrict__ b2,
    const float* __restrict__ Wo, const float* __restrict__ bo,
    float* W3e, float* W3d, float* biasE, float* biasD, float* W2Wo, float* b2Wo)
{
  int blk = blockIdx.x;
  if (blk < 2304) {
    const float* W; f16* o; int N, base;
    if      (blk < 1024) { W=Wse;   o=pWse;   N=256;  base=0; }
    else if (blk < 2048) { W=Wsd;   o=pWsd;   N=256;  base=1024; }
    else if (blk < 2176) { W=Wih_e; o=pWih_e; N=1024; base=2048; }
    else                 { W=Wih_d; o=pWih_d; N=1024; base=2176; }
    int tid = (blk - base)*256 + threadIdx.x;
    int l = tid & 63;
    int nct = N >> 4;
    int ctg = (tid >> 6) % nct;
    int kfg = (tid >> 6) / nct;
    int k0  = kfg*32 + ((l>>4)<<3);
    int col = ctg*16 + (l&15);
    f16x8 v;
#pragma unroll
    for (int i=0;i<8;++i) v[i] = (f16)W[(size_t)(k0+i)*N + col];
    *(f16x8*)(o + (size_t)tid*8) = v;
    return;
  }
  if (blk < 2432) {
    const float* W; signed char* o; int base;
    if (blk < 2368) { W=Whh_e; o=pWhh_e; base=2304; }
    else            { W=Whh_d; o=pWhh_d; base=2368; }
    int tid = (blk - base)*256 + threadIdx.x;
    int l = tid & 63;
    int unit = tid >> 6;                        // [kfg(4)][ctg(64)]
    int kfg = unit >> 6, ctg = unit & 63;
    int k0  = kfg*64 + ((l>>4)<<4);
    int col = ctg*16 + (l&15);
    signed char* dst = o + ((size_t)unit*64 + l)*16;
#pragma unroll
    for (int e=0;e<16;++e) {
      int q = __float2int_rn(W[(size_t)(k0+e)*1024 + col] * 1024.0f);
      q = q > 127 ? 127 : (q < -127 ? -127 : q);
      dst[e] = (signed char)q;
    }
    return;
  }
  int bid = blk - 2432, tid = threadIdx.x;
  if (bid < 4) {
    int j = bid*256 + tid;
    float s0=0,s1=0,s2=0,sb=0;
    for (int m=0;m<256;++m) {
      float wv = Wih_e[(size_t)(256+m)*1024 + j];
      s0 += Wpe[m]*wv; s1 += Wpe[256+m]*wv; s2 += Wpe[512+m]*wv; sb += bpe[m]*wv;
    }
    W3e[j]=s0; W3e[1024+j]=s1; W3e[2048+j]=s2;
    biasE[j] = bih_e[j] + bhh_e[j] + sb;
  } else if (bid < 8) {
    int j = (bid-4)*256 + tid;
    float s0=0,s1=0,s2=0,sb=0;
    for (int m=0;m<256;++m) {
      float wv = Wih_d[(size_t)(256+m)*1024 + j];
      s0 += Wpd[m]*wv; s1 += Wpd[256+m]*wv; s2 += Wpd[512+m]*wv; sb += bpd[m]*wv;
    }
    W3d[j]=s0; W3d[1024+j]=s1; W3d[2048+j]=s2;
    biasD[j] = bih_d[j] + bhh_d[j] + sb;
  } else if (bid == 8) {
    int c = tid;
    float s0=0,s1=0,s2=0;
    for (int m=0;m<256;++m) {
      float wv = W2[(size_t)c*256+m];
      s0 += wv*Wo[m*3+0]; s1 += wv*Wo[m*3+1]; s2 += wv*Wo[m*3+2];
    }
    W2Wo[c*3+0]=s0; W2Wo[c*3+1]=s1; W2Wo[c*3+2]=s2;
  } else {
    if (tid < 192) {
      int j = tid >> 6, lane = tid & 63;
      float s = 0.f;
      for (int m=lane;m<256;m+=64) s += b2[m]*Wo[m*3+j];
#pragma unroll
      for (int msk=1;msk<64;msk<<=1) s += __shfl_xor(s, msk);
      if (lane==0) b2Wo[j] = s + bo[j];
    }
  }
}

// ======== fused GEMM (R13 verbatim): preg = (A@Ws + bs)@Wih + bias [+pos@W3]
__global__ __launch_bounds__(256) void k_gemm_fused(
    const float* __restrict__ A0, const f16* __restrict__ W0,
    const float* __restrict__ bs0, const f16* __restrict__ Wih0,
    const float* __restrict__ bias0, f16* __restrict__ P0, int nb0, int T0,
    const float* __restrict__ pos0, const float* __restrict__ W3f0,
    const float* __restrict__ A1, const f16* __restrict__ W1,
    const float* __restrict__ bs1, const f16* __restrict__ Wih1,
    const float* __restrict__ bias1, f16* __restrict__ P1, int T1)
{
  __shared__ f16 aLDS[2][64*64];   // 16 KB
  __shared__ f16 sLDS[64*256];     // 32 KB
  const int tid = threadIdx.x, l = tid & 63, w = tid >> 6;
  const int li = l & 15, hi = l >> 4;
  const int bx = blockIdx.x;
  const float *Ap, *bs, *bias, *posf, *W3f; const f16 *Wp, *Wih; f16* P; int rblk, T;
  if (bx < nb0) { Ap=A0; Wp=W0; bs=bs0; Wih=Wih0; bias=bias0; P=P0; rblk=bx*64;       T=T0; posf=pos0; W3f=W3f0; }
  else          { Ap=A1; Wp=W1; bs=bs1; Wih=Wih1; bias=bias1; P=P1; rblk=(bx-nb0)*64; T=T1; posf=nullptr; W3f=nullptr; }
  const int t = rblk >> 10, b0 = rblk & 1023;

  f32x4 acc[4][4];
#pragma unroll
  for (int a=0;a<4;++a)
#pragma unroll
    for (int b=0;b<4;++b) acc[a][b] = (f32x4){0.f,0.f,0.f,0.f};

  const int srow = tid >> 2, kseg = tid & 3;
  const float* Arow = Ap + ((size_t)(b0 + srow)*T + t)*8192 + kseg*16;

  float4 fA0,fA1,fA2,fA3, fB0,fB1,fB2,fB3;
#define LOADA_A(ti_) { const float* Aq = Arow + (ti_)*64;                      \
    fA0 = *(const float4*)Aq;     fA1 = *(const float4*)(Aq+4);                \
    fA2 = *(const float4*)(Aq+8); fA3 = *(const float4*)(Aq+12); }
#define LOADA_B(ti_) { const float* Aq = Arow + (ti_)*64;                      \
    fB0 = *(const float4*)Aq;     fB1 = *(const float4*)(Aq+4);                \
    fB2 = *(const float4*)(Aq+8); fB3 = *(const float4*)(Aq+12); }
#define MFMA_TILE(buf_, kfg0_)                                                 \
  _Pragma("unroll")                                                            \
  for (int kf = 0; kf < 2; ++kf) {                                             \
    f16x8 afr[4], bfr[4];                                                      \
    _Pragma("unroll")                                                          \
    for (int rt=0; rt<4; ++rt) {                                               \
      int row = rt*16 + li;                                                    \
      afr[rt] = *(f16x8*)&aLDS[buf_][row*64 + (((kf*4) + hi) ^ (row&7))*8];    \
    }                                                                          \
    _Pragma("unroll")                                                          \
    for (int ct=0; ct<4; ++ct) {                                               \
      int ctg = w*4 + ct;                                                      \
      bfr[ct] = *(const f16x8*)(Wp + ((size_t)(((kfg0_)+kf)*16 + ctg)*64 + l)*8); \
    }                                                                          \
    _Pragma("unroll")                                                          \
    for (int rt=0; rt<4; ++rt)                                                 \
      _Pragma("unroll")                                                        \
      for (int ct=0; ct<4; ++ct)                                               \
        acc[rt][ct] = MFMA16(afr[rt], bfr[ct], acc[rt][ct]);                   \
  }
#define STAGE1_STEP(F0,F1,F2,F3, RELOAD, buf_, ti_) {                          \
    f16x8 w0, w1;                                                              \
    w0[0]=(f16)F0.x; w0[1]=(f16)F0.y; w0[2]=(f16)F0.z; w0[3]=(f16)F0.w;        \
    w0[4]=(f16)F1.x; w0[5]=(f16)F1.y; w0[6]=(f16)F1.z; w0[7]=(f16)F1.w;        \
    w1[0]=(f16)F2.x; w1[1]=(f16)F2.y; w1[2]=(f16)F2.z; w1[3]=(f16)F2.w;        \
    w1[4]=(f16)F3.x; w1[5]=(f16)F3.y; w1[6]=(f16)F3.z; w1[7]=(f16)F3.w;        \
    bar_plain();                                                               \
    *(f16x8*)&aLDS[buf_][srow*64 + ((kseg*2    ) ^ (srow&7))*8] = w0;          \
    *(f16x8*)&aLDS[buf_][srow*64 + ((kseg*2 + 1) ^ (srow&7))*8] = w1;          \
    { int tn = ((ti_)+2 < 128) ? (ti_)+2 : 127; RELOAD(tn); }                  \
    bar_lgkm();                                                                \
    MFMA_TILE(buf_, (ti_)*2)                                                   \
  }

  LOADA_A(0); LOADA_B(1);
  for (int ti = 0; ti < 128; ti += 2) {
    STAGE1_STEP(fA0,fA1,fA2,fA3, LOADA_A, 0, ti)
    STAGE1_STEP(fB0,fB1,fB2,fB3, LOADA_B, 1, ti+1)
  }
#undef LOADA_A
#undef LOADA_B
#undef MFMA_TILE
#undef STAGE1_STEP
  bar_plain();
#pragma unroll
  for (int ct=0; ct<4; ++ct) {
    int col = (w*4 + ct)*16 + li;
    float bv = bs[col];
    int slot = col >> 3;
#pragma unroll
    for (int rt=0; rt<4; ++rt)
#pragma unroll
      for (int i=0;i<4;++i) {
        int row = rt*16 + hi*4 + i;
        sLDS[row*256 + ((slot ^ (row&7))<<3) + (col&7)] = (f16)(acc[rt][ct][i] + bv);
      }
  }
  float pe[4][4][3];
  if (posf) {
#pragma unroll
    for (int rt=0; rt<4; ++rt)
#pragma unroll
      for (int i=0;i<4;++i) {
        int brow = b0 + rt*16 + hi*4 + i;
        const float* pq = posf + ((size_t)brow*T + t)*3;
        pe[rt][i][0]=pq[0]; pe[rt][i][1]=pq[1]; pe[rt][i][2]=pq[2];
      }
  }
  __syncthreads();
  const int bblk0 = b0 >> 4;
#pragma unroll
  for (int cg=0; cg<4; ++cg) {
    f32x4 a2[4][4];
#pragma unroll
    for (int a=0;a<4;++a)
#pragma unroll
      for (int b=0;b<4;++b) a2[a][b] = (f32x4){0.f,0.f,0.f,0.f};
#pragma unroll
    for (int kfg=0; kfg<8; ++kfg) {
      f16x8 afr[4], bfr[4];
#pragma unroll
      for (int rt=0; rt<4; ++rt) {
        int row = rt*16 + li;
        afr[rt] = *(f16x8*)&sLDS[row*256 + (((kfg*4 + hi) ^ (row&7))<<3)];
      }
#pragma unroll
      for (int ct=0; ct<4; ++ct) {
        int ctg2 = cg*16 + w*4 + ct;
        bfr[ct] = *(const f16x8*)(Wih + ((size_t)(kfg*64 + ctg2)*64 + l)*8);
      }
#pragma unroll
      for (int rt=0; rt<4; ++rt)
#pragma unroll
        for (int ct=0; ct<4; ++ct)
          a2[rt][ct] = MFMA16(afr[rt], bfr[ct], a2[rt][ct]);
    }
#pragma unroll
    for (int ct=0; ct<4; ++ct) {
      const int ctg2 = cg*16 + w*4 + ct;
      const float bv = bias[ctg2*16 + li];
      float w30=0.f, w31=0.f, w32=0.f;
      if (posf) { int gc = ctg2*16 + li; w30=W3f[gc]; w31=W3f[1024+gc]; w32=W3f[2048+gc]; }
#pragma unroll
      for (int rt=0; rt<4; ++rt) {
        f16x4 o;
#pragma unroll
        for (int i=0;i<4;++i) {
          float v = a2[rt][ct][i] + bv;
          if (posf) v += pe[rt][i][0]*w30 + pe[rt][i][1]*w31 + pe[rt][i][2]*w32;
          o[i] = (f16)v;
        }
        *(f16x4*)(P + ((size_t)((bblk0 + rt)*T + t)*64 + ctg2)*256 + l*4) = o;
      }
    }
  }
}

// ================= recurrent kernel: RESIDENT WEIGHTS =======================
// 64 blocks x 16 rows, 256 threads (4 waves, 1 wave/SIMD -> up to 512 VGPR).
// wave w owns h-cols [w*64,+64): ctg = q*16 + w*4 + jj (jj=0..3).
// Whh (i8): kf0-1 held in VGPRs (128/wave), kf2-3 in wave-private persistent
// LDS (128 KB). Zero weight re-streaming; per step = 64 MFMAs + gate VALU.
__global__ __launch_bounds__(256, 1) void k_rnn(
    const f16* __restrict__ pregE,   // [b_blk][5][64][64][4]  (pos+bias folded)
    const f16* __restrict__ pregD,   // [b_blk][25][64][64][4] (bias folded)
    const signed char* __restrict__ Whh_e_p, const signed char* __restrict__ Whh_d_p,
    const float* __restrict__ W3d, const float* __restrict__ dec_pos,
    const float* __restrict__ W2Wo, const float* __restrict__ b2Wo,
    float* __restrict__ out)         // (B,25,3)
{
  __shared__ signed char pLDS[4][2][16][1024]; // 128 KB persistent kf2-3
  __shared__ signed char hBuf[2][16*256];      // 8 KB i8, 16B-slot ^= row&7
  __shared__ float dpart[25][16][3];           // 4.7 KB
  const int tid = threadIdx.x, l = tid & 63, w = tid >> 6;   // w = 0..3
  const int li = l & 15, hi = l >> 4;
  const int bblk = blockIdx.x, rb = bblk*16;
  const float SC = 1.0f/130048.0f;             // 1/(1024*127)

  for (int i=tid; i<25*16*3; i+=256) ((float*)dpart)[i] = 0.f;

  float c_st[4][4];                            // [jj][i]
#pragma unroll
  for (int j=0;j<4;++j)
#pragma unroll
    for (int i=0;i<4;++i) c_st[j][i]=0.f;

  i32x4 wreg[32];                              // kf0-1: [kk*16 + f], f=(q<<2)|jj

#define LOADWREG(WP)                                                          \
  _Pragma("unroll") for (int kk=0;kk<2;++kk)                                  \
  _Pragma("unroll") for (int f=0;f<16;++f) {                                  \
    int ctg = (f>>2)*16 + w*4 + (f&3);                                        \
    wreg[kk*16+f] = *(const i32x4*)((WP) + ((size_t)(kk*64 + ctg)*64 + l)*16); \
  }
#define LOADWLDS(WP)                                                          \
  _Pragma("unroll") for (int kk=0;kk<2;++kk)                                  \
  _Pragma("unroll") for (int f=0;f<16;++f) {                                  \
    int ctg = (f>>2)*16 + w*4 + (f&3);                                        \
    const signed char* gp = (WP) + ((size_t)((kk+2)*64 + ctg)*64 + l)*16;     \
    __builtin_amdgcn_global_load_lds((gu32*)gp, (lu32*)&pLDS[w][kk][f][0], 16, 0, 0); \
  }
#define AHK(ah, hB, kf) ah = *(i32x4*)&(hB)[li*256 + ((((kf)*4)+hi) ^ (li&7))*16];
#define MFMA_ALL(hB) {                                                        \
  i32x4 ah;                                                                   \
  _Pragma("unroll") for (int kk=0;kk<2;++kk) {                                \
    AHK(ah, hB, kk)                                                           \
    _Pragma("unroll") for (int f=0;f<16;++f)                                  \
      acc[f>>2][f&3] = MFMAI8(ah, wreg[kk*16+f], acc[f>>2][f&3]);             \
  }                                                                           \
  _Pragma("unroll") for (int kk=0;kk<2;++kk) {                                \
    AHK(ah, hB, kk+2)                                                         \
    _Pragma("unroll") for (int f=0;f<16;++f) {                                \
      i32x4 b = *(i32x4*)&pLDS[w][kk][f][l*16];                               \
      acc[f>>2][f&3] = MFMAI8(ah, b, acc[f>>2][f&3]);                         \
    }                                                                         \
  } }
#define LOADPV(dst, base, t_)                                                 \
  _Pragma("unroll")                                                           \
  for (int q=0;q<4;++q)                                                       \
    _Pragma("unroll")                                                         \
    for (int jj=0;jj<4;++jj)                                                  \
      dst[q][jj] = *(const f16x4*)((base) + ((size_t)(t_)*16384 + (size_t)(q*16 + w*4 + jj)*256 + l*4));
#define COPYPV()                                                              \
  _Pragma("unroll")                                                           \
  for (int q=0;q<4;++q)                                                       \
    _Pragma("unroll")                                                         \
    for (int jj=0;jj<4;++jj) pvA[q][jj] = pvB[q][jj];
#define ACCZERO()                                                             \
  i32x4 acc[4][4];                                                            \
  _Pragma("unroll")                                                           \
  for (int q=0;q<4;++q)                                                       \
    _Pragma("unroll")                                                         \
    for (int jj=0;jj<4;++jj) acc[q][jj] = (i32x4){0,0,0,0};
#define HWRITE(hB, r, hc, hval)                                               \
  (hB)[(r)*256 + ((((hc)>>4) ^ ((r)&7))<<4) + ((hc)&15)] =                    \
      (signed char)__float2int_rn((hval)*127.0f);
#define VMW0() { asm volatile("s_waitcnt vmcnt(0)" ::: "memory");             \
                 __builtin_amdgcn_sched_barrier(0); }

  const f16* prE = pregE + (size_t)bblk*5*16384;
  const f16* prD = pregD + (size_t)bblk*25*16384;
  f16x4 pvA[4][4], pvB[4][4];

  // load encoder weights (one-time)
  LOADWLDS(Whh_e_p)
  LOADWREG(Whh_e_p)
  LOADPV(pvA, prE, 0)
  VMW0()                          // pLDS (wave-private) + pv + wreg retired
  __syncthreads();                // dpart init visible

  // ---------------- encoder (gate = pv + acc: bias+pos pre-folded) ---------
  for (int t=0;t<5;++t) {
    if (t+1 < 5) LOADPV(pvB, prE, t+1)
    ACCZERO()
    if (t > 0) MFMA_ALL(hBuf[(t-1)&1])
#pragma unroll
    for (int i=0;i<4;++i) {
      int r = hi*4 + i;
#pragma unroll
      for (int jj=0;jj<4;++jj) {
        int hc = w*64 + jj*16 + li;
        float gq[4];
#pragma unroll
        for (int q=0;q<4;++q)
          gq[q] = (float)pvA[q][jj][i] + (float)acc[q][jj][i]*SC;
        float cn = sigm(gq[1])*c_st[jj][i] + sigm(gq[0])*tanh_(gq[2]);
        c_st[jj][i] = cn;
        float h = sigm(gq[3])*tanh_(cn);
        HWRITE(hBuf[t&1], r, hc, h)
      }
    }
    if (t+1 < 5) { COPYPV() }
    bar_lgkm();                   // h[t] visible
  }

  // ---------------- switch to decoder weights + constants ----------------
  LOADWLDS(Whh_d_p)               // own-wave region; enc reads finished
  LOADWREG(Whh_d_p)
  float w3r[4][4][3];             // [jj][q][d]
#pragma unroll
  for (int jj=0;jj<4;++jj)
#pragma unroll
    for (int q=0;q<4;++q) {
      int gc = q*256 + w*64 + jj*16 + li;
      w3r[jj][q][0]=W3d[gc]; w3r[jj][q][1]=W3d[1024+gc]; w3r[jj][q][2]=W3d[2048+gc];
    }
  float w2r[4][3];
#pragma unroll
  for (int jj=0;jj<4;++jj) {
    int hc = w*64 + jj*16 + li;
    w2r[jj][0]=W2Wo[hc*3+0]; w2r[jj][1]=W2Wo[hc*3+1]; w2r[jj][2]=W2Wo[hc*3+2];
  }
  const float b2w0 = b2Wo[0], b2w1 = b2Wo[1], b2w2 = b2Wo[2];
  float pp[4][3];
#pragma unroll
  for (int i=0;i<4;++i) {
    int r = rb + hi*4 + i;
    pp[i][0]=dec_pos[r*3+0]; pp[i][1]=dec_pos[r*3+1]; pp[i][2]=dec_pos[r*3+2];
  }
  LOADPV(pvA, prD, 0)
  VMW0()                          // dec pLDS writes + pv retired

  // ---------------- decoder (1 barrier/step) ----------------
  // enc t=4 wrote hBuf[0]; dec step t reads hBuf[t&1], writes hBuf[(t+1)&1].
  for (int t=0;t<25;++t) {
    if (t+1 < 25) LOADPV(pvB, prD, t+1)
    ACCZERO()
    MFMA_ALL(hBuf[t&1])
    float dpar[4][3];
#pragma unroll
    for (int i=0;i<4;++i){ dpar[i][0]=0.f; dpar[i][1]=0.f; dpar[i][2]=0.f; }
#pragma unroll
    for (int i=0;i<4;++i) {
      int r = hi*4 + i;
#pragma unroll
      for (int jj=0;jj<4;++jj) {
        int hc = w*64 + jj*16 + li;
        float gq[4];
#pragma unroll
        for (int q=0;q<4;++q)
          gq[q] = (float)pvA[q][jj][i] + (float)acc[q][jj][i]*SC
                + pp[i][0]*w3r[jj][q][0] + pp[i][1]*w3r[jj][q][1] + pp[i][2]*w3r[jj][q][2];
        float cn = sigm(gq[1])*c_st[jj][i] + sigm(gq[0])*tanh_(gq[2]);
        c_st[jj][i] = cn;
        float h = sigm(gq[3])*tanh_(cn);
        HWRITE(hBuf[(t+1)&1], r, hc, h)
        dpar[i][0] += h*w2r[jj][0];
        dpar[i][1] += h*w2r[jj][1];
        dpar[i][2] += h*w2r[jj][2];
      }
    }
#pragma unroll
    for (int m=1;m<16;m<<=1)
#pragma unroll
      for (int i=0;i<4;++i) {
        dpar[i][0] += __shfl_xor(dpar[i][0], m);
        dpar[i][1] += __shfl_xor(dpar[i][1], m);
        dpar[i][2] += __shfl_xor(dpar[i][2], m);
      }
    if (li==0) {
#pragma unroll
      for (int i=0;i<4;++i) {
        int r = hi*4 + i;
        atomicAdd(&dpart[t][r][0], dpar[i][0]);
        atomicAdd(&dpart[t][r][1], dpar[i][1]);
        atomicAdd(&dpart[t][r][2], dpar[i][2]);
      }
    }
    if (t+1 < 25) { COPYPV() }
    bar_lgkm();                   // h[t+1] + dpart[t] visible
#pragma unroll
    for (int i=0;i<4;++i) {
      int r = hi*4 + i;
      float p0 = pp[i][0] + b2w0 + dpart[t][r][0];
      float p1 = pp[i][1] + b2w1 + dpart[t][r][1];
      float p2 = pp[i][2] + b2w2 + dpart[t][r][2];
      float inv = frsq(p0*p0+p1*p1+p2*p2);
      pp[i][0]=p0*inv; pp[i][1]=p1*inv; pp[i][2]=p2*inv;
      if (w==0 && li==0) {
        float* o = out + (size_t)(rb+r)*75 + t*3;
        o[0]=pp[i][0]; o[1]=pp[i][1]; o[2]=pp[i][2];
      }
    }
  }
#undef LOADWREG
#undef LOADWLDS
#undef AHK
#undef MFMA_ALL
#undef LOADPV
#undef COPYPV
#undef ACCZERO
#undef HWRITE
#undef VMW0
}

// ================= launch =================
extern "C" void kernel_launch(void* const* d_in, const int* in_sizes, int n_in,
                              void* d_out, int out_size, void* d_ws, size_t ws_size,
                              hipStream_t stream)
{
  const float* enc_pos = (const float*)d_in[0];
  const float* enc_sal = (const float*)d_in[1];
  const float* dec_pos = (const float*)d_in[2];
  const float* dec_sal = (const float*)d_in[3];
  const float* Wpe  = (const float*)d_in[4];
  const float* bpe  = (const float*)d_in[5];
  const float* Wse  = (const float*)d_in[6];
  const float* bse  = (const float*)d_in[7];
  const float* Wih_e= (const float*)d_in[8];
  const float* Whh_e= (const float*)d_in[9];
  const float* bih_e= (const float*)d_in[10];
  const float* bhh_e= (const float*)d_in[11];
  const float* Wih_d= (const float*)d_in[12];
  const float* Whh_d= (const float*)d_in[13];
  const float* bih_d= (const float*)d_in[14];
  const float* bhh_d= (const float*)d_in[15];
  const float* Wpd  = (const float*)d_in[16];
  const float* bpd  = (const float*)d_in[17];
  const float* Wsd  = (const float*)d_in[18];
  const float* bsd  = (const float*)d_in[19];
  const float* W2   = (const float*)d_in[20];
  const float* b2   = (const float*)d_in[21];
  const float* Wo   = (const float*)d_in[22];
  const float* bo   = (const float*)d_in[23];

  char* ws = (char*)d_ws;
  f16* pWse   = (f16*)(ws + OFF_WSE_P);
  f16* pWsd   = (f16*)(ws + OFF_WSD_P);
  f16* pWih_e = (f16*)(ws + OFF_WIHE_P);
  f16* pWih_d = (f16*)(ws + OFF_WIHD_P);
  signed char* pWhh_e = (signed char*)(ws + OFF_WHHE_P);
  signed char* pWhh_d = (signed char*)(ws + OFF_WHHD_P);
  float* W3e  = (float*)(ws + OFF_W3E);
  float* W3d  = (float*)(ws + OFF_W3D);
  float* W2WoP= (float*)(ws + OFF_W2WO);
  float* biasE= (float*)(ws + OFF_BIASE);
  float* biasD= (float*)(ws + OFF_BIASD);
  float* b2WoP= (float*)(ws + OFF_B2WO);
  f16* pregE  = (f16*)(ws + OFF_PREGE);
  f16* pregD  = (f16*)(ws + OFF_PREGD);
  float* out  = (float*)d_out;

  hipLaunchKernelGGL(k_prep, dim3(2442), dim3(256), 0, stream,
                     Wse, Wsd, Wih_e, Wih_d, Whh_e, Whh_d,
                     pWse, pWsd, pWih_e, pWih_d, pWhh_e, pWhh_d,
                     Wpe, bpe, bih_e, bhh_e, Wpd, bpd, bih_d, bhh_d,
                     W2, b2, Wo, bo,
                     W3e, W3d, biasE, biasD, W2WoP, b2WoP);
  // fused sal-projection + pre-gate GEMM: enc tiles [0,80), dec [80,480)
  hipLaunchKernelGGL(k_gemm_fused, dim3(480), dim3(256), 0, stream,
                     enc_sal, pWse, bse, pWih_e, biasE, pregE, 80, 5, enc_pos, W3e,
                     dec_sal, pWsd, bsd, pWih_d, biasD, pregD, 25);
  // recurrent kernel with resident weights (4 waves, 1 wave/SIMD)
  hipLaunchKernelGGL(k_rnn, dim3(64), dim3(256), 0, stream,
                     pregE, pregD, pWhh_e, pWhh_d,
                     W3d, dec_pos, W2WoP, b2WoP, out);
}

// Round 16
// 480.120 us; speedup vs baseline: 1.5764x; 1.0888x over previous
//
#include <hip/hip_runtime.h>

typedef _Float16 f16;
typedef _Float16 f16x4 __attribute__((ext_vector_type(4)));
typedef _Float16 f16x8 __attribute__((ext_vector_type(8)));
typedef float    f32x4 __attribute__((ext_vector_type(4)));
typedef int      i32x4 __attribute__((ext_vector_type(4)));
typedef unsigned int u32;

#define MFMA16(a,b,c) __builtin_amdgcn_mfma_f32_16x16x32_f16((a),(b),(c),0,0,0)
#define MFMAI8(a,b,c) __builtin_amdgcn_mfma_i32_16x16x64_i8((a),(b),(c),0,0,0)

typedef __attribute__((address_space(1))) const u32 gu32;
typedef __attribute__((address_space(3))) u32 lu32;

static __device__ __forceinline__ float frcp(float x){ float r; asm("v_rcp_f32 %0, %1" : "=v"(r) : "v"(x)); return r; }
static __device__ __forceinline__ float frsq(float x){ float r; asm("v_rsq_f32 %0, %1" : "=v"(r) : "v"(x)); return r; }
static __device__ __forceinline__ float sigm(float x){ return frcp(1.0f + __expf(-x)); }
static __device__ __forceinline__ float tanh_(float x){ return 1.0f - 2.0f*frcp(1.0f + __expf(2.0f*x)); }

static __device__ __forceinline__ void bar_lgkm(){
  asm volatile("s_waitcnt lgkmcnt(0)" ::: "memory");
  __builtin_amdgcn_s_barrier();
  asm volatile("" ::: "memory");
}
static __device__ __forceinline__ void bar_plain(){
  asm volatile("" ::: "memory");
  __builtin_amdgcn_s_barrier();
  asm volatile("" ::: "memory");
}

// ---------------- workspace layout (bytes) ----------------
static constexpr size_t OFF_WSE_P  = 0;
static constexpr size_t OFF_WSD_P  = OFF_WSE_P  + (size_t)8192*256*2;
static constexpr size_t OFF_WIHE_P = OFF_WSD_P  + (size_t)8192*256*2;
static constexpr size_t OFF_WIHD_P = OFF_WIHE_P + (size_t)256*1024*2;
static constexpr size_t OFF_WHHE_P = OFF_WIHD_P + (size_t)256*1024*2;    // i8
static constexpr size_t OFF_WHHD_P = OFF_WHHE_P + (size_t)256*1024;      // i8
static constexpr size_t OFF_W3E    = OFF_WHHD_P + (size_t)256*1024;
static constexpr size_t OFF_W3D    = OFF_W3E   + (size_t)3*1024*4;
static constexpr size_t OFF_W2WO   = OFF_W3D   + (size_t)3*1024*4;
static constexpr size_t OFF_BIASE  = OFF_W2WO  + (size_t)256*3*4;
static constexpr size_t OFF_BIASD  = OFF_BIASE + (size_t)1024*4;
static constexpr size_t OFF_B2WO   = OFF_BIASD + (size_t)1024*4;
static constexpr size_t OFF_PREGE  = OFF_B2WO  + 256;
static constexpr size_t OFF_PREGD  = OFF_PREGE + (size_t)5120*1024*2;
static constexpr size_t OFF_END    = OFF_PREGD + (size_t)25600*1024*2;

// ================= prep: pack weights + small folds (unchanged) =============
__global__ __launch_bounds__(256) void k_prep(
    const float* __restrict__ Wse, const float* __restrict__ Wsd,
    const float* __restrict__ Wih_e, const float* __restrict__ Wih_d,
    const float* __restrict__ Whh_e, const float* __restrict__ Whh_d,
    f16* pWse, f16* pWsd, f16* pWih_e, f16* pWih_d,
    signed char* pWhh_e, signed char* pWhh_d,
    const float* __restrict__ Wpe, const float* __restrict__ bpe,
    const float* __restrict__ bih_e, const float* __restrict__ bhh_e,
    const float* __restrict__ Wpd, const float* __restrict__ bpd,
    const float* __restrict__ bih_d, const float* __restrict__ bhh_d,
    const float* __restrict__ W2, const float* __restrict__ b2,
    const float* __restrict__ Wo, const float* __restrict__ bo,
    float* W3e, float* W3d, float* biasE, float* biasD, float* W2Wo, float* b2Wo)
{
  int blk = blockIdx.x;
  if (blk < 2304) {
    const float* W; f16* o; int N, base;
    if      (blk < 1024) { W=Wse;   o=pWse;   N=256;  base=0; }
    else if (blk < 2048) { W=Wsd;   o=pWsd;   N=256;  base=1024; }
    else if (blk < 2176) { W=Wih_e; o=pWih_e; N=1024; base=2048; }
    else                 { W=Wih_d; o=pWih_d; N=1024; base=2176; }
    int tid = (blk - base)*256 + threadIdx.x;
    int l = tid & 63;
    int nct = N >> 4;
    int ctg = (tid >> 6) % nct;
    int kfg = (tid >> 6) / nct;
    int k0  = kfg*32 + ((l>>4)<<3);
    int col = ctg*16 + (l&15);
    f16x8 v;
#pragma unroll
    for (int i=0;i<8;++i) v[i] = (f16)W[(size_t)(k0+i)*N + col];
    *(f16x8*)(o + (size_t)tid*8) = v;
    return;
  }
  if (blk < 2432) {
    const float* W; signed char* o; int base;
    if (blk < 2368) { W=Whh_e; o=pWhh_e; base=2304; }
    else            { W=Whh_d; o=pWhh_d; base=2368; }
    int tid = (blk - base)*256 + threadIdx.x;
    int l = tid & 63;
    int unit = tid >> 6;                        // [kfg(4)][ctg(64)]
    int kfg = unit >> 6, ctg = unit & 63;
    int k0  = kfg*64 + ((l>>4)<<4);
    int col = ctg*16 + (l&15);
    signed char* dst = o + ((size_t)unit*64 + l)*16;
#pragma unroll
    for (int e=0;e<16;++e) {
      int q = __float2int_rn(W[(size_t)(k0+e)*1024 + col] * 1024.0f);
      q = q > 127 ? 127 : (q < -127 ? -127 : q);
      dst[e] = (signed char)q;
    }
    return;
  }
  int bid = blk - 2432, tid = threadIdx.x;
  if (bid < 4) {
    int j = bid*256 + tid;
    float s0=0,s1=0,s2=0,sb=0;
    for (int m=0;m<256;++m) {
      float wv = Wih_e[(size_t)(256+m)*1024 + j];
      s0 += Wpe[m]*wv; s1 += Wpe[256+m]*wv; s2 += Wpe[512+m]*wv; sb += bpe[m]*wv;
    }
    W3e[j]=s0; W3e[1024+j]=s1; W3e[2048+j]=s2;
    biasE[j] = bih_e[j] + bhh_e[j] + sb;
  } else if (bid < 8) {
    int j = (bid-4)*256 + tid;
    float s0=0,s1=0,s2=0,sb=0;
    for (int m=0;m<256;++m) {
      float wv = Wih_d[(size_t)(256+m)*1024 + j];
      s0 += Wpd[m]*wv; s1 += Wpd[256+m]*wv; s2 += Wpd[512+m]*wv; sb += bpd[m]*wv;
    }
    W3d[j]=s0; W3d[1024+j]=s1; W3d[2048+j]=s2;
    biasD[j] = bih_d[j] + bhh_d[j] + sb;
  } else if (bid == 8) {
    int c = tid;
    float s0=0,s1=0,s2=0;
    for (int m=0;m<256;++m) {
      float wv = W2[(size_t)c*256+m];
      s0 += wv*Wo[m*3+0]; s1 += wv*Wo[m*3+1]; s2 += wv*Wo[m*3+2];
    }
    W2Wo[c*3+0]=s0; W2Wo[c*3+1]=s1; W2Wo[c*3+2]=s2;
  } else {
    if (tid < 192) {
      int j = tid >> 6, lane = tid & 63;
      float s = 0.f;
      for (int m=lane;m<256;m+=64) s += b2[m]*Wo[m*3+j];
#pragma unroll
      for (int msk=1;msk<64;msk<<=1) s += __shfl_xor(s, msk);
      if (lane==0) b2Wo[j] = s + bo[j];
    }
  }
}

// ======== fused GEMM (unchanged): preg = (A@Ws + bs)@Wih + bias [+pos@W3] ===
__global__ __launch_bounds__(256) void k_gemm_fused(
    const float* __restrict__ A0, const f16* __restrict__ W0,
    const float* __restrict__ bs0, const f16* __restrict__ Wih0,
    const float* __restrict__ bias0, f16* __restrict__ P0, int nb0, int T0,
    const float* __restrict__ pos0, const float* __restrict__ W3f0,
    const float* __restrict__ A1, const f16* __restrict__ W1,
    const float* __restrict__ bs1, const f16* __restrict__ Wih1,
    const float* __restrict__ bias1, f16* __restrict__ P1, int T1)
{
  __shared__ f16 aLDS[2][64*64];   // 16 KB
  __shared__ f16 sLDS[64*256];     // 32 KB
  const int tid = threadIdx.x, l = tid & 63, w = tid >> 6;
  const int li = l & 15, hi = l >> 4;
  const int bx = blockIdx.x;
  const float *Ap, *bs, *bias, *posf, *W3f; const f16 *Wp, *Wih; f16* P; int rblk, T;
  if (bx < nb0) { Ap=A0; Wp=W0; bs=bs0; Wih=Wih0; bias=bias0; P=P0; rblk=bx*64;       T=T0; posf=pos0; W3f=W3f0; }
  else          { Ap=A1; Wp=W1; bs=bs1; Wih=Wih1; bias=bias1; P=P1; rblk=(bx-nb0)*64; T=T1; posf=nullptr; W3f=nullptr; }
  const int t = rblk >> 10, b0 = rblk & 1023;

  f32x4 acc[4][4];
#pragma unroll
  for (int a=0;a<4;++a)
#pragma unroll
    for (int b=0;b<4;++b) acc[a][b] = (f32x4){0.f,0.f,0.f,0.f};

  const int srow = tid >> 2, kseg = tid & 3;
  const float* Arow = Ap + ((size_t)(b0 + srow)*T + t)*8192 + kseg*16;

  float4 fA0,fA1,fA2,fA3, fB0,fB1,fB2,fB3;
#define LOADA_A(ti_) { const float* Aq = Arow + (ti_)*64;                      \
    fA0 = *(const float4*)Aq;     fA1 = *(const float4*)(Aq+4);                \
    fA2 = *(const float4*)(Aq+8); fA3 = *(const float4*)(Aq+12); }
#define LOADA_B(ti_) { const float* Aq = Arow + (ti_)*64;                      \
    fB0 = *(const float4*)Aq;     fB1 = *(const float4*)(Aq+4);                \
    fB2 = *(const float4*)(Aq+8); fB3 = *(const float4*)(Aq+12); }
#define MFMA_TILE(buf_, kfg0_)                                                 \
  _Pragma("unroll")                                                            \
  for (int kf = 0; kf < 2; ++kf) {                                             \
    f16x8 afr[4], bfr[4];                                                      \
    _Pragma("unroll")                                                          \
    for (int rt=0; rt<4; ++rt) {                                               \
      int row = rt*16 + li;                                                    \
      afr[rt] = *(f16x8*)&aLDS[buf_][row*64 + (((kf*4) + hi) ^ (row&7))*8];    \
    }                                                                          \
    _Pragma("unroll")                                                          \
    for (int ct=0; ct<4; ++ct) {                                               \
      int ctg = w*4 + ct;                                                      \
      bfr[ct] = *(const f16x8*)(Wp + ((size_t)(((kfg0_)+kf)*16 + ctg)*64 + l)*8); \
    }                                                                          \
    _Pragma("unroll")                                                          \
    for (int rt=0; rt<4; ++rt)                                                 \
      _Pragma("unroll")                                                        \
      for (int ct=0; ct<4; ++ct)                                               \
        acc[rt][ct] = MFMA16(afr[rt], bfr[ct], acc[rt][ct]);                   \
  }
#define STAGE1_STEP(F0,F1,F2,F3, RELOAD, buf_, ti_) {                          \
    f16x8 w0, w1;                                                              \
    w0[0]=(f16)F0.x; w0[1]=(f16)F0.y; w0[2]=(f16)F0.z; w0[3]=(f16)F0.w;        \
    w0[4]=(f16)F1.x; w0[5]=(f16)F1.y; w0[6]=(f16)F1.z; w0[7]=(f16)F1.w;        \
    w1[0]=(f16)F2.x; w1[1]=(f16)F2.y; w1[2]=(f16)F2.z; w1[3]=(f16)F2.w;        \
    w1[4]=(f16)F3.x; w1[5]=(f16)F3.y; w1[6]=(f16)F3.z; w1[7]=(f16)F3.w;        \
    bar_plain();                                                               \
    *(f16x8*)&aLDS[buf_][srow*64 + ((kseg*2    ) ^ (srow&7))*8] = w0;          \
    *(f16x8*)&aLDS[buf_][srow*64 + ((kseg*2 + 1) ^ (srow&7))*8] = w1;          \
    { int tn = ((ti_)+2 < 128) ? (ti_)+2 : 127; RELOAD(tn); }                  \
    bar_lgkm();                                                                \
    MFMA_TILE(buf_, (ti_)*2)                                                   \
  }

  LOADA_A(0); LOADA_B(1);
  for (int ti = 0; ti < 128; ti += 2) {
    STAGE1_STEP(fA0,fA1,fA2,fA3, LOADA_A, 0, ti)
    STAGE1_STEP(fB0,fB1,fB2,fB3, LOADA_B, 1, ti+1)
  }
#undef LOADA_A
#undef LOADA_B
#undef MFMA_TILE
#undef STAGE1_STEP
  bar_plain();
#pragma unroll
  for (int ct=0; ct<4; ++ct) {
    int col = (w*4 + ct)*16 + li;
    float bv = bs[col];
    int slot = col >> 3;
#pragma unroll
    for (int rt=0; rt<4; ++rt)
#pragma unroll
      for (int i=0;i<4;++i) {
        int row = rt*16 + hi*4 + i;
        sLDS[row*256 + ((slot ^ (row&7))<<3) + (col&7)] = (f16)(acc[rt][ct][i] + bv);
      }
  }
  float pe[4][4][3];
  if (posf) {
#pragma unroll
    for (int rt=0; rt<4; ++rt)
#pragma unroll
      for (int i=0;i<4;++i) {
        int brow = b0 + rt*16 + hi*4 + i;
        const float* pq = posf + ((size_t)brow*T + t)*3;
        pe[rt][i][0]=pq[0]; pe[rt][i][1]=pq[1]; pe[rt][i][2]=pq[2];
      }
  }
  __syncthreads();
  const int bblk0 = b0 >> 4;
#pragma unroll
  for (int cg=0; cg<4; ++cg) {
    f32x4 a2[4][4];
#pragma unroll
    for (int a=0;a<4;++a)
#pragma unroll
      for (int b=0;b<4;++b) a2[a][b] = (f32x4){0.f,0.f,0.f,0.f};
#pragma unroll
    for (int kfg=0; kfg<8; ++kfg) {
      f16x8 afr[4], bfr[4];
#pragma unroll
      for (int rt=0; rt<4; ++rt) {
        int row = rt*16 + li;
        afr[rt] = *(f16x8*)&sLDS[row*256 + (((kfg*4 + hi) ^ (row&7))<<3)];
      }
#pragma unroll
      for (int ct=0; ct<4; ++ct) {
        int ctg2 = cg*16 + w*4 + ct;
        bfr[ct] = *(const f16x8*)(Wih + ((size_t)(kfg*64 + ctg2)*64 + l)*8);
      }
#pragma unroll
      for (int rt=0; rt<4; ++rt)
#pragma unroll
        for (int ct=0; ct<4; ++ct)
          a2[rt][ct] = MFMA16(afr[rt], bfr[ct], a2[rt][ct]);
    }
#pragma unroll
    for (int ct=0; ct<4; ++ct) {
      const int ctg2 = cg*16 + w*4 + ct;
      const float bv = bias[ctg2*16 + li];
      float w30=0.f, w31=0.f, w32=0.f;
      if (posf) { int gc = ctg2*16 + li; w30=W3f[gc]; w31=W3f[1024+gc]; w32=W3f[2048+gc]; }
#pragma unroll
      for (int rt=0; rt<4; ++rt) {
        f16x4 o;
#pragma unroll
        for (int i=0;i<4;++i) {
          float v = a2[rt][ct][i] + bv;
          if (posf) v += pe[rt][i][0]*w30 + pe[rt][i][1]*w31 + pe[rt][i][2]*w32;
          o[i] = (f16)v;
        }
        *(f16x4*)(P + ((size_t)((bblk0 + rt)*T + t)*64 + ctg2)*256 + l*4) = o;
      }
    }
  }
}

// ================= recurrent kernel: RESIDENT WEIGHTS, 8 waves ==============
// 64 blocks x 16 rows, 512 threads (8 waves), amdgpu_waves_per_eu(2,2) ->
// 256-VGPR budget (defeats the 128-reg occupancy heuristic that spilled R15).
// wave w owns h-cols [w*32,+32): ctg = q*16 + w*2 + j (j=0..1).
// Whh (i8): kf0-1 in VGPRs (64/wave), kf2-3 in wave-private persistent LDS
// (128 KB). Zero re-streaming; per step = 32 MFMAs/wave + gate VALU.
__global__ __launch_bounds__(512) __attribute__((amdgpu_waves_per_eu(2,2)))
void k_rnn(
    const f16* __restrict__ pregE,   // [b_blk][5][64][64][4]  (pos+bias folded)
    const f16* __restrict__ pregD,   // [b_blk][25][64][64][4] (bias folded)
    const signed char* __restrict__ Whh_e_p, const signed char* __restrict__ Whh_d_p,
    const float* __restrict__ W3d, const float* __restrict__ dec_pos,
    const float* __restrict__ W2Wo, const float* __restrict__ b2Wo,
    float* __restrict__ out)         // (B,25,3)
{
  __shared__ signed char pLDS[8][2][8][1024]; // 128 KB persistent kf2-3
  __shared__ signed char hBuf[2][16*256];     // 8 KB i8, 16B-slot ^= row&7
  __shared__ float dpart[25][16][3];          // 4.7 KB
  const int tid = threadIdx.x, l = tid & 63, w = tid >> 6;   // w = 0..7
  const int li = l & 15, hi = l >> 4;
  const int bblk = blockIdx.x, rb = bblk*16;
  const float SC = 1.0f/130048.0f;            // 1/(1024*127)

  for (int i=tid; i<25*16*3; i+=512) ((float*)dpart)[i] = 0.f;

  float c_st[2][4];                           // [j][i]
#pragma unroll
  for (int j=0;j<2;++j)
#pragma unroll
    for (int i=0;i<4;++i) c_st[j][i]=0.f;

  i32x4 wreg[16];                             // kf0-1: [kk*8 + f], f=q*2+j

#define LOADWREG(WP)                                                          \
  _Pragma("unroll") for (int kk=0;kk<2;++kk)                                  \
  _Pragma("unroll") for (int f=0;f<8;++f) {                                   \
    int ctg = (f>>1)*16 + w*2 + (f&1);                                        \
    wreg[kk*8+f] = *(const i32x4*)((WP) + ((size_t)(kk*64 + ctg)*64 + l)*16); \
  }
#define LOADWLDS(WP)                                                          \
  _Pragma("unroll") for (int kk=0;kk<2;++kk)                                  \
  _Pragma("unroll") for (int f=0;f<8;++f) {                                   \
    int ctg = (f>>1)*16 + w*2 + (f&1);                                        \
    const signed char* gp = (WP) + ((size_t)((kk+2)*64 + ctg)*64 + l)*16;     \
    __builtin_amdgcn_global_load_lds((gu32*)gp, (lu32*)&pLDS[w][kk][f][0], 16, 0, 0); \
  }
#define AHK(ah, hB, kf) ah = *(i32x4*)&(hB)[li*256 + ((((kf)*4)+hi) ^ (li&7))*16];
#define MFMA_ALL(hB) {                                                        \
  i32x4 ah;                                                                   \
  _Pragma("unroll") for (int kk=0;kk<2;++kk) {                                \
    AHK(ah, hB, kk)                                                           \
    _Pragma("unroll") for (int f=0;f<8;++f)                                   \
      acc[f>>1][f&1] = MFMAI8(ah, wreg[kk*8+f], acc[f>>1][f&1]);              \
  }                                                                           \
  _Pragma("unroll") for (int kk=0;kk<2;++kk) {                                \
    AHK(ah, hB, kk+2)                                                         \
    _Pragma("unroll") for (int f=0;f<8;++f) {                                 \
      i32x4 b = *(i32x4*)&pLDS[w][kk][f][l*16];                               \
      acc[f>>1][f&1] = MFMAI8(ah, b, acc[f>>1][f&1]);                         \
    }                                                                         \
  } }
#define LOADPV(dst, base, t_)                                                 \
  _Pragma("unroll")                                                           \
  for (int q=0;q<4;++q)                                                       \
    _Pragma("unroll")                                                         \
    for (int j=0;j<2;++j)                                                     \
      dst[q][j] = *(const f16x4*)((base) + ((size_t)(t_)*16384 + (size_t)(q*16 + w*2 + j)*256 + l*4));
#define COPYPV()                                                              \
  _Pragma("unroll")                                                           \
  for (int q=0;q<4;++q)                                                       \
    _Pragma("unroll")                                                         \
    for (int j=0;j<2;++j) pvA[q][j] = pvB[q][j];
#define ACCZERO()                                                             \
  i32x4 acc[4][2];                                                            \
  _Pragma("unroll")                                                           \
  for (int q=0;q<4;++q)                                                       \
    _Pragma("unroll")                                                         \
    for (int j=0;j<2;++j) acc[q][j] = (i32x4){0,0,0,0};
#define HWRITE(hB, r, hc, hval)                                               \
  (hB)[(r)*256 + ((((hc)>>4) ^ ((r)&7))<<4) + ((hc)&15)] =                    \
      (signed char)__float2int_rn((hval)*127.0f);
#define VMW0() { asm volatile("s_waitcnt vmcnt(0)" ::: "memory");             \
                 __builtin_amdgcn_sched_barrier(0); }

  const f16* prE = pregE + (size_t)bblk*5*16384;
  const f16* prD = pregD + (size_t)bblk*25*16384;
  f16x4 pvA[4][2], pvB[4][2];

  // one-time encoder weight load
  LOADWLDS(Whh_e_p)
  LOADWREG(Whh_e_p)
  LOADPV(pvA, prE, 0)
  VMW0()                          // pLDS (wave-private) + wreg + pv retired
  __syncthreads();                // dpart init visible

  // ---------------- encoder (gate = pv + acc: bias+pos pre-folded) ---------
  for (int t=0;t<5;++t) {
    if (t+1 < 5) LOADPV(pvB, prE, t+1)
    ACCZERO()
    if (t > 0) MFMA_ALL(hBuf[(t-1)&1])
#pragma unroll
    for (int i=0;i<4;++i) {
      int r = hi*4 + i;
#pragma unroll
      for (int j=0;j<2;++j) {
        int hc = w*32 + j*16 + li;
        float gq[4];
#pragma unroll
        for (int q=0;q<4;++q)
          gq[q] = (float)pvA[q][j][i] + (float)acc[q][j][i]*SC;
        float cn = sigm(gq[1])*c_st[j][i] + sigm(gq[0])*tanh_(gq[2]);
        c_st[j][i] = cn;
        float h = sigm(gq[3])*tanh_(cn);
        HWRITE(hBuf[t&1], r, hc, h)
      }
    }
    if (t+1 < 5) { COPYPV() }
    bar_lgkm();                   // h[t] visible
  }

  // ---------------- switch to decoder weights + constants ----------------
  LOADWLDS(Whh_d_p)               // own-wave region; enc reads finished
  LOADWREG(Whh_d_p)
  float w3r[2][4][3];             // [j][q][d]
#pragma unroll
  for (int j=0;j<2;++j)
#pragma unroll
    for (int q=0;q<4;++q) {
      int gc = q*256 + w*32 + j*16 + li;
      w3r[j][q][0]=W3d[gc]; w3r[j][q][1]=W3d[1024+gc]; w3r[j][q][2]=W3d[2048+gc];
    }
  float w2r[2][3];
#pragma unroll
  for (int j=0;j<2;++j) {
    int hc = w*32 + j*16 + li;
    w2r[j][0]=W2Wo[hc*3+0]; w2r[j][1]=W2Wo[hc*3+1]; w2r[j][2]=W2Wo[hc*3+2];
  }
  const float b2w0 = b2Wo[0], b2w1 = b2Wo[1], b2w2 = b2Wo[2];
  float pp[4][3];
#pragma unroll
  for (int i=0;i<4;++i) {
    int r = rb + hi*4 + i;
    pp[i][0]=dec_pos[r*3+0]; pp[i][1]=dec_pos[r*3+1]; pp[i][2]=dec_pos[r*3+2];
  }
  LOADPV(pvA, prD, 0)
  VMW0()                          // dec pLDS writes + wreg + pv retired

  // ---------------- decoder (1 barrier/step) ----------------
  // enc t=4 wrote hBuf[0]; dec step t reads hBuf[t&1], writes hBuf[(t+1)&1].
  for (int t=0;t<25;++t) {
    if (t+1 < 25) LOADPV(pvB, prD, t+1)
    ACCZERO()
    MFMA_ALL(hBuf[t&1])
    float dpar[4][3];
#pragma unroll
    for (int i=0;i<4;++i){ dpar[i][0]=0.f; dpar[i][1]=0.f; dpar[i][2]=0.f; }
#pragma unroll
    for (int i=0;i<4;++i) {
      int r = hi*4 + i;
#pragma unroll
      for (int j=0;j<2;++j) {
        int hc = w*32 + j*16 + li;
        float gq[4];
#pragma unroll
        for (int q=0;q<4;++q)
          gq[q] = (float)pvA[q][j][i] + (float)acc[q][j][i]*SC
                + pp[i][0]*w3r[j][q][0] + pp[i][1]*w3r[j][q][1] + pp[i][2]*w3r[j][q][2];
        float cn = sigm(gq[1])*c_st[j][i] + sigm(gq[0])*tanh_(gq[2]);
        c_st[j][i] = cn;
        float h = sigm(gq[3])*tanh_(cn);
        HWRITE(hBuf[(t+1)&1], r, hc, h)
        dpar[i][0] += h*w2r[j][0];
        dpar[i][1] += h*w2r[j][1];
        dpar[i][2] += h*w2r[j][2];
      }
    }
#pragma unroll
    for (int m=1;m<16;m<<=1)
#pragma unroll
      for (int i=0;i<4;++i) {
        dpar[i][0] += __shfl_xor(dpar[i][0], m);
        dpar[i][1] += __shfl_xor(dpar[i][1], m);
        dpar[i][2] += __shfl_xor(dpar[i][2], m);
      }
    if (li==0) {
#pragma unroll
      for (int i=0;i<4;++i) {
        int r = hi*4 + i;
        atomicAdd(&dpart[t][r][0], dpar[i][0]);
        atomicAdd(&dpart[t][r][1], dpar[i][1]);
        atomicAdd(&dpart[t][r][2], dpar[i][2]);
      }
    }
    if (t+1 < 25) { COPYPV() }
    bar_lgkm();                   // h[t+1] + dpart[t] visible
#pragma unroll
    for (int i=0;i<4;++i) {
      int r = hi*4 + i;
      float p0 = pp[i][0] + b2w0 + dpart[t][r][0];
      float p1 = pp[i][1] + b2w1 + dpart[t][r][1];
      float p2 = pp[i][2] + b2w2 + dpart[t][r][2];
      float inv = frsq(p0*p0+p1*p1+p2*p2);
      pp[i][0]=p0*inv; pp[i][1]=p1*inv; pp[i][2]=p2*inv;
      if (w==0 && li==0) {
        float* o = out + (size_t)(rb+r)*75 + t*3;
        o[0]=pp[i][0]; o[1]=pp[i][1]; o[2]=pp[i][2];
      }
    }
  }
#undef LOADWREG
#undef LOADWLDS
#undef AHK
#undef MFMA_ALL
#undef LOADPV
#undef COPYPV
#undef ACCZERO
#undef HWRITE
#undef VMW0
}

// ================= launch =================
extern "C" void kernel_launch(void* const* d_in, const int* in_sizes, int n_in,
                              void* d_out, int out_size, void* d_ws, size_t ws_size,
                              hipStream_t stream)
{
  const float* enc_pos = (const float*)d_in[0];
  const float* enc_sal = (const float*)d_in[1];
  const float* dec_pos = (const float*)d_in[2];
  const float* dec_sal = (const float*)d_in[3];
  const float* Wpe  = (const float*)d_in[4];
  const float* bpe  = (const float*)d_in[5];
  const float* Wse  = (const float*)d_in[6];
  const float* bse  = (const float*)d_in[7];
  const float* Wih_e= (const float*)d_in[8];
  const float* Whh_e= (const float*)d_in[9];
  const float* bih_e= (const float*)d_in[10];
  const float* bhh_e= (const float*)d_in[11];
  const float* Wih_d= (const float*)d_in[12];
  const float* Whh_d= (const float*)d_in[13];
  const float* bih_d= (const float*)d_in[14];
  const float* bhh_d= (const float*)d_in[15];
  const float* Wpd  = (const float*)d_in[16];
  const float* bpd  = (const float*)d_in[17];
  const float* Wsd  = (const float*)d_in[18];
  const float* bsd  = (const float*)d_in[19];
  const float* W2   = (const float*)d_in[20];
  const float* b2   = (const float*)d_in[21];
  const float* Wo   = (const float*)d_in[22];
  const float* bo   = (const float*)d_in[23];

  char* ws = (char*)d_ws;
  f16* pWse   = (f16*)(ws + OFF_WSE_P);
  f16* pWsd   = (f16*)(ws + OFF_WSD_P);
  f16* pWih_e = (f16*)(ws + OFF_WIHE_P);
  f16* pWih_d = (f16*)(ws + OFF_WIHD_P);
  signed char* pWhh_e = (signed char*)(ws + OFF_WHHE_P);
  signed char* pWhh_d = (signed char*)(ws + OFF_WHHD_P);
  float* W3e  = (float*)(ws + OFF_W3E);
  float* W3d  = (float*)(ws + OFF_W3D);
  float* W2WoP= (float*)(ws + OFF_W2WO);
  float* biasE= (float*)(ws + OFF_BIASE);
  float* biasD= (float*)(ws + OFF_BIASD);
  float* b2WoP= (float*)(ws + OFF_B2WO);
  f16* pregE  = (f16*)(ws + OFF_PREGE);
  f16* pregD  = (f16*)(ws + OFF_PREGD);
  float* out  = (float*)d_out;

  hipLaunchKernelGGL(k_prep, dim3(2442), dim3(256), 0, stream,
                     Wse, Wsd, Wih_e, Wih_d, Whh_e, Whh_d,
                     pWse, pWsd, pWih_e, pWih_d, pWhh_e, pWhh_d,
                     Wpe, bpe, bih_e, bhh_e, Wpd, bpd, bih_d, bhh_d,
                     W2, b2, Wo, bo,
                     W3e, W3d, biasE, biasD, W2WoP, b2WoP);
  // fused sal-projection + pre-gate GEMM: enc tiles [0,80), dec [80,480)
  hipLaunchKernelGGL(k_gemm_fused, dim3(480), dim3(256), 0, stream,
                     enc_sal, pWse, bse, pWih_e, biasE, pregE, 80, 5, enc_pos, W3e,
                     dec_sal, pWsd, bsd, pWih_d, biasD, pregD, 25);
  // recurrent kernel with resident weights (8 waves, 2 waves/EU -> 256 VGPR)
  hipLaunchKernelGGL(k_rnn, dim3(64), dim3(512), 0, stream,
                     pregE, pregD, pWhh_e, pWhh_d,
                     W3d, dec_pos, W2WoP, b2WoP, out);
}

// Round 17
// 468.942 us; speedup vs baseline: 1.6139x; 1.0238x over previous
//
#include <hip/hip_runtime.h>

typedef _Float16 f16;
typedef _Float16 f16x4 __attribute__((ext_vector_type(4)));
typedef _Float16 f16x8 __attribute__((ext_vector_type(8)));
typedef float    f32x4 __attribute__((ext_vector_type(4)));
typedef int      i32x4 __attribute__((ext_vector_type(4)));
typedef unsigned int u32;

#define MFMA16(a,b,c) __builtin_amdgcn_mfma_f32_16x16x32_f16((a),(b),(c),0,0,0)
#define MFMAI8(a,b,c) __builtin_amdgcn_mfma_i32_16x16x64_i8((a),(b),(c),0,0,0)

typedef __attribute__((address_space(1))) const u32 gu32;
typedef __attribute__((address_space(3))) u32 lu32;

static __device__ __forceinline__ float frcp(float x){ float r; asm("v_rcp_f32 %0, %1" : "=v"(r) : "v"(x)); return r; }
static __device__ __forceinline__ float frsq(float x){ float r; asm("v_rsq_f32 %0, %1" : "=v"(r) : "v"(x)); return r; }
static __device__ __forceinline__ float sigm(float x){ return frcp(1.0f + __expf(-x)); }
static __device__ __forceinline__ float tanh_(float x){ return 1.0f - 2.0f*frcp(1.0f + __expf(2.0f*x)); }

static __device__ __forceinline__ void bar_lgkm(){
  asm volatile("s_waitcnt lgkmcnt(0)" ::: "memory");
  __builtin_amdgcn_s_barrier();
  asm volatile("" ::: "memory");
}
static __device__ __forceinline__ void bar_plain(){
  asm volatile("" ::: "memory");
  __builtin_amdgcn_s_barrier();
  asm volatile("" ::: "memory");
}

// ---------------- workspace layout (bytes) ----------------
static constexpr size_t OFF_WSE_P  = 0;
static constexpr size_t OFF_WSD_P  = OFF_WSE_P  + (size_t)8192*256*2;
static constexpr size_t OFF_WIHE_P = OFF_WSD_P  + (size_t)8192*256*2;
static constexpr size_t OFF_WIHD_P = OFF_WIHE_P + (size_t)256*1024*2;
static constexpr size_t OFF_WHHE_P = OFF_WIHD_P + (size_t)256*1024*2;    // i8
static constexpr size_t OFF_WHHD_P = OFF_WHHE_P + (size_t)256*1024;      // i8
static constexpr size_t OFF_W3E    = OFF_WHHD_P + (size_t)256*1024;
static constexpr size_t OFF_W3D    = OFF_W3E   + (size_t)3*1024*4;
static constexpr size_t OFF_W2WO   = OFF_W3D   + (size_t)3*1024*4;
static constexpr size_t OFF_BIASE  = OFF_W2WO  + (size_t)256*3*4;
static constexpr size_t OFF_BIASD  = OFF_BIASE + (size_t)1024*4;
static constexpr size_t OFF_B2WO   = OFF_BIASD + (size_t)1024*4;
static constexpr size_t OFF_PREGE  = OFF_B2WO  + 256;
static constexpr size_t OFF_PREGD  = OFF_PREGE + (size_t)5120*1024*2;
static constexpr size_t OFF_END    = OFF_PREGD + (size_t)25600*1024*2;

// ================= prep: pack weights + small folds (unchanged) =============
__global__ __launch_bounds__(256) void k_prep(
    const float* __restrict__ Wse, const float* __restrict__ Wsd,
    const float* __restrict__ Wih_e, const float* __restrict__ Wih_d,
    const float* __restrict__ Whh_e, const float* __restrict__ Whh_d,
    f16* pWse, f16* pWsd, f16* pWih_e, f16* pWih_d,
    signed char* pWhh_e, signed char* pWhh_d,
    const float* __restrict__ Wpe, const float* __restrict__ bpe,
    const float* __restrict__ bih_e, const float* __restrict__ bhh_e,
    const float* __restrict__ Wpd, const float* __restrict__ bpd,
    const float* __restrict__ bih_d, const float* __restrict__ bhh_d,
    const float* __restrict__ W2, const float* __restrict__ b2,
    const float* __restrict__ Wo, const float* __restrict__ bo,
    float* W3e, float* W3d, float* biasE, float* biasD, float* W2Wo, float* b2Wo)
{
  int blk = blockIdx.x;
  if (blk < 2304) {
    const float* W; f16* o; int N, base;
    if      (blk < 1024) { W=Wse;   o=pWse;   N=256;  base=0; }
    else if (blk < 2048) { W=Wsd;   o=pWsd;   N=256;  base=1024; }
    else if (blk < 2176) { W=Wih_e; o=pWih_e; N=1024; base=2048; }
    else                 { W=Wih_d; o=pWih_d; N=1024; base=2176; }
    int tid = (blk - base)*256 + threadIdx.x;
    int l = tid & 63;
    int nct = N >> 4;
    int ctg = (tid >> 6) % nct;
    int kfg = (tid >> 6) / nct;
    int k0  = kfg*32 + ((l>>4)<<3);
    int col = ctg*16 + (l&15);
    f16x8 v;
#pragma unroll
    for (int i=0;i<8;++i) v[i] = (f16)W[(size_t)(k0+i)*N + col];
    *(f16x8*)(o + (size_t)tid*8) = v;
    return;
  }
  if (blk < 2432) {
    const float* W; signed char* o; int base;
    if (blk < 2368) { W=Whh_e; o=pWhh_e; base=2304; }
    else            { W=Whh_d; o=pWhh_d; base=2368; }
    int tid = (blk - base)*256 + threadIdx.x;
    int l = tid & 63;
    int unit = tid >> 6;                        // [kfg(4)][ctg(64)]
    int kfg = unit >> 6, ctg = unit & 63;
    int k0  = kfg*64 + ((l>>4)<<4);
    int col = ctg*16 + (l&15);
    signed char* dst = o + ((size_t)unit*64 + l)*16;
#pragma unroll
    for (int e=0;e<16;++e) {
      int q = __float2int_rn(W[(size_t)(k0+e)*1024 + col] * 1024.0f);
      q = q > 127 ? 127 : (q < -127 ? -127 : q);
      dst[e] = (signed char)q;
    }
    return;
  }
  int bid = blk - 2432, tid = threadIdx.x;
  if (bid < 4) {
    int j = bid*256 + tid;
    float s0=0,s1=0,s2=0,sb=0;
    for (int m=0;m<256;++m) {
      float wv = Wih_e[(size_t)(256+m)*1024 + j];
      s0 += Wpe[m]*wv; s1 += Wpe[256+m]*wv; s2 += Wpe[512+m]*wv; sb += bpe[m]*wv;
    }
    W3e[j]=s0; W3e[1024+j]=s1; W3e[2048+j]=s2;
    biasE[j] = bih_e[j] + bhh_e[j] + sb;
  } else if (bid < 8) {
    int j = (bid-4)*256 + tid;
    float s0=0,s1=0,s2=0,sb=0;
    for (int m=0;m<256;++m) {
      float wv = Wih_d[(size_t)(256+m)*1024 + j];
      s0 += Wpd[m]*wv; s1 += Wpd[256+m]*wv; s2 += Wpd[512+m]*wv; sb += bpd[m]*wv;
    }
    W3d[j]=s0; W3d[1024+j]=s1; W3d[2048+j]=s2;
    biasD[j] = bih_d[j] + bhh_d[j] + sb;
  } else if (bid == 8) {
    int c = tid;
    float s0=0,s1=0,s2=0;
    for (int m=0;m<256;++m) {
      float wv = W2[(size_t)c*256+m];
      s0 += wv*Wo[m*3+0]; s1 += wv*Wo[m*3+1]; s2 += wv*Wo[m*3+2];
    }
    W2Wo[c*3+0]=s0; W2Wo[c*3+1]=s1; W2Wo[c*3+2]=s2;
  } else {
    if (tid < 192) {
      int j = tid >> 6, lane = tid & 63;
      float s = 0.f;
      for (int m=lane;m<256;m+=64) s += b2[m]*Wo[m*3+j];
#pragma unroll
      for (int msk=1;msk<64;msk<<=1) s += __shfl_xor(s, msk);
      if (lane==0) b2Wo[j] = s + bo[j];
    }
  }
}

// ======== fused GEMM (unchanged): preg = (A@Ws + bs)@Wih + bias [+pos@W3] ===
__global__ __launch_bounds__(256) void k_gemm_fused(
    const float* __restrict__ A0, const f16* __restrict__ W0,
    const float* __restrict__ bs0, const f16* __restrict__ Wih0,
    const float* __restrict__ bias0, f16* __restrict__ P0, int nb0, int T0,
    const float* __restrict__ pos0, const float* __restrict__ W3f0,
    const float* __restrict__ A1, const f16* __restrict__ W1,
    const float* __restrict__ bs1, const f16* __restrict__ Wih1,
    const float* __restrict__ bias1, f16* __restrict__ P1, int T1)
{
  __shared__ f16 aLDS[2][64*64];   // 16 KB
  __shared__ f16 sLDS[64*256];     // 32 KB
  const int tid = threadIdx.x, l = tid & 63, w = tid >> 6;
  const int li = l & 15, hi = l >> 4;
  const int bx = blockIdx.x;
  const float *Ap, *bs, *bias, *posf, *W3f; const f16 *Wp, *Wih; f16* P; int rblk, T;
  if (bx < nb0) { Ap=A0; Wp=W0; bs=bs0; Wih=Wih0; bias=bias0; P=P0; rblk=bx*64;       T=T0; posf=pos0; W3f=W3f0; }
  else          { Ap=A1; Wp=W1; bs=bs1; Wih=Wih1; bias=bias1; P=P1; rblk=(bx-nb0)*64; T=T1; posf=nullptr; W3f=nullptr; }
  const int t = rblk >> 10, b0 = rblk & 1023;

  f32x4 acc[4][4];
#pragma unroll
  for (int a=0;a<4;++a)
#pragma unroll
    for (int b=0;b<4;++b) acc[a][b] = (f32x4){0.f,0.f,0.f,0.f};

  const int srow = tid >> 2, kseg = tid & 3;
  const float* Arow = Ap + ((size_t)(b0 + srow)*T + t)*8192 + kseg*16;

  float4 fA0,fA1,fA2,fA3, fB0,fB1,fB2,fB3;
#define LOADA_A(ti_) { const float* Aq = Arow + (ti_)*64;                      \
    fA0 = *(const float4*)Aq;     fA1 = *(const float4*)(Aq+4);                \
    fA2 = *(const float4*)(Aq+8); fA3 = *(const float4*)(Aq+12); }
#define LOADA_B(ti_) { const float* Aq = Arow + (ti_)*64;                      \
    fB0 = *(const float4*)Aq;     fB1 = *(const float4*)(Aq+4);                \
    fB2 = *(const float4*)(Aq+8); fB3 = *(const float4*)(Aq+12); }
#define MFMA_TILE(buf_, kfg0_)                                                 \
  _Pragma("unroll")                                                            \
  for (int kf = 0; kf < 2; ++kf) {                                             \
    f16x8 afr[4], bfr[4];                                                      \
    _Pragma("unroll")                                                          \
    for (int rt=0; rt<4; ++rt) {                                               \
      int row = rt*16 + li;                                                    \
      afr[rt] = *(f16x8*)&aLDS[buf_][row*64 + (((kf*4) + hi) ^ (row&7))*8];    \
    }                                                                          \
    _Pragma("unroll")                                                          \
    for (int ct=0; ct<4; ++ct) {                                               \
      int ctg = w*4 + ct;                                                      \
      bfr[ct] = *(const f16x8*)(Wp + ((size_t)(((kfg0_)+kf)*16 + ctg)*64 + l)*8); \
    }                                                                          \
    _Pragma("unroll")                                                          \
    for (int rt=0; rt<4; ++rt)                                                 \
      _Pragma("unroll")                                                        \
      for (int ct=0; ct<4; ++ct)                                               \
        acc[rt][ct] = MFMA16(afr[rt], bfr[ct], acc[rt][ct]);                   \
  }
#define STAGE1_STEP(F0,F1,F2,F3, RELOAD, buf_, ti_) {                          \
    f16x8 w0, w1;                                                              \
    w0[0]=(f16)F0.x; w0[1]=(f16)F0.y; w0[2]=(f16)F0.z; w0[3]=(f16)F0.w;        \
    w0[4]=(f16)F1.x; w0[5]=(f16)F1.y; w0[6]=(f16)F1.z; w0[7]=(f16)F1.w;        \
    w1[0]=(f16)F2.x; w1[1]=(f16)F2.y; w1[2]=(f16)F2.z; w1[3]=(f16)F2.w;        \
    w1[4]=(f16)F3.x; w1[5]=(f16)F3.y; w1[6]=(f16)F3.z; w1[7]=(f16)F3.w;        \
    bar_plain();                                                               \
    *(f16x8*)&aLDS[buf_][srow*64 + ((kseg*2    ) ^ (srow&7))*8] = w0;          \
    *(f16x8*)&aLDS[buf_][srow*64 + ((kseg*2 + 1) ^ (srow&7))*8] = w1;          \
    { int tn = ((ti_)+2 < 128) ? (ti_)+2 : 127; RELOAD(tn); }                  \
    bar_lgkm();                                                                \
    MFMA_TILE(buf_, (ti_)*2)                                                   \
  }

  LOADA_A(0); LOADA_B(1);
  for (int ti = 0; ti < 128; ti += 2) {
    STAGE1_STEP(fA0,fA1,fA2,fA3, LOADA_A, 0, ti)
    STAGE1_STEP(fB0,fB1,fB2,fB3, LOADA_B, 1, ti+1)
  }
#undef LOADA_A
#undef LOADA_B
#undef MFMA_TILE
#undef STAGE1_STEP
  bar_plain();
#pragma unroll
  for (int ct=0; ct<4; ++ct) {
    int col = (w*4 + ct)*16 + li;
    float bv = bs[col];
    int slot = col >> 3;
#pragma unroll
    for (int rt=0; rt<4; ++rt)
#pragma unroll
      for (int i=0;i<4;++i) {
        int row = rt*16 + hi*4 + i;
        sLDS[row*256 + ((slot ^ (row&7))<<3) + (col&7)] = (f16)(acc[rt][ct][i] + bv);
      }
  }
  float pe[4][4][3];
  if (posf) {
#pragma unroll
    for (int rt=0; rt<4; ++rt)
#pragma unroll
      for (int i=0;i<4;++i) {
        int brow = b0 + rt*16 + hi*4 + i;
        const float* pq = posf + ((size_t)brow*T + t)*3;
        pe[rt][i][0]=pq[0]; pe[rt][i][1]=pq[1]; pe[rt][i][2]=pq[2];
      }
  }
  __syncthreads();
  const int bblk0 = b0 >> 4;
#pragma unroll
  for (int cg=0; cg<4; ++cg) {
    f32x4 a2[4][4];
#pragma unroll
    for (int a=0;a<4;++a)
#pragma unroll
      for (int b=0;b<4;++b) a2[a][b] = (f32x4){0.f,0.f,0.f,0.f};
#pragma unroll
    for (int kfg=0; kfg<8; ++kfg) {
      f16x8 afr[4], bfr[4];
#pragma unroll
      for (int rt=0; rt<4; ++rt) {
        int row = rt*16 + li;
        afr[rt] = *(f16x8*)&sLDS[row*256 + (((kfg*4 + hi) ^ (row&7))<<3)];
      }
#pragma unroll
      for (int ct=0; ct<4; ++ct) {
        int ctg2 = cg*16 + w*4 + ct;
        bfr[ct] = *(const f16x8*)(Wih + ((size_t)(kfg*64 + ctg2)*64 + l)*8);
      }
#pragma unroll
      for (int rt=0; rt<4; ++rt)
#pragma unroll
        for (int ct=0; ct<4; ++ct)
          a2[rt][ct] = MFMA16(afr[rt], bfr[ct], a2[rt][ct]);
    }
#pragma unroll
    for (int ct=0; ct<4; ++ct) {
      const int ctg2 = cg*16 + w*4 + ct;
      const float bv = bias[ctg2*16 + li];
      float w30=0.f, w31=0.f, w32=0.f;
      if (posf) { int gc = ctg2*16 + li; w30=W3f[gc]; w31=W3f[1024+gc]; w32=W3f[2048+gc]; }
#pragma unroll
      for (int rt=0; rt<4; ++rt) {
        f16x4 o;
#pragma unroll
        for (int i=0;i<4;++i) {
          float v = a2[rt][ct][i] + bv;
          if (posf) v += pe[rt][i][0]*w30 + pe[rt][i][1]*w31 + pe[rt][i][2]*w32;
          o[i] = (f16)v;
        }
        *(f16x4*)(P + ((size_t)((bblk0 + rt)*T + t)*64 + ctg2)*256 + l*4) = o;
      }
    }
  }
}

// ================= recurrent kernel: RESIDENT WEIGHTS, 16 waves =============
// 64 blocks x 16 rows, 1024 threads (16 waves). Wave w owns h-cols [w*16,+16):
// ctg = q*16 + w (ONE col-tile per gate per wave).
// Whh (i8): kf0-1 in VGPRs (32/wave), kf2-3 in wave-private persistent LDS
// (128 KB). True register need ~110-120 < 128 -> no spill even at the
// allocator's 128-reg occupancy target (the failure mode of R7/9/15/16).
// pv single-buffered (latency hides under MFMA + 4 waves/SIMD TLP);
// W3/W2 gathered per step from LDS into transient regs.
__global__ __launch_bounds__(1024) void k_rnn(
    const f16* __restrict__ pregE,   // [b_blk][5][64][64][4]  (pos+bias folded)
    const f16* __restrict__ pregD,   // [b_blk][25][64][64][4] (bias folded)
    const signed char* __restrict__ Whh_e_p, const signed char* __restrict__ Whh_d_p,
    const float* __restrict__ W3d, const float* __restrict__ dec_pos,
    const float* __restrict__ W2Wo, const float* __restrict__ b2Wo,
    float* __restrict__ out)         // (B,25,3)
{
  __shared__ signed char pLDS[16][2][4][1024]; // 128 KB persistent kf2-3
  __shared__ signed char hBuf[2][16*256];      // 8 KB i8, 16B-slot ^= row&7
  __shared__ f16 W3h[3*1024];                  // 6 KB (f16 fold of W3d)
  __shared__ float dpart[25][16][3];           // 4.7 KB
  const int tid = threadIdx.x, l = tid & 63, w = tid >> 6;   // w = 0..15
  const int li = l & 15, hi = l >> 4;
  const int bblk = blockIdx.x, rb = bblk*16;
  const float SC = 1.0f/130048.0f;             // 1/(1024*127)

  for (int i=tid;i<3072;i+=1024) W3h[i] = (f16)W3d[i];
  for (int i=tid; i<25*16*3; i+=1024) ((float*)dpart)[i] = 0.f;

  float c_st[4];                               // [i] (1 col per thread)
#pragma unroll
  for (int i=0;i<4;++i) c_st[i]=0.f;

  i32x4 wreg[8];                               // kf0-1: [kk*4 + q]

#define LOADWREG(WP)                                                          \
  _Pragma("unroll") for (int kk=0;kk<2;++kk)                                  \
  _Pragma("unroll") for (int q=0;q<4;++q) {                                   \
    int ctg = q*16 + w;                                                       \
    wreg[kk*4+q] = *(const i32x4*)((WP) + ((size_t)(kk*64 + ctg)*64 + l)*16); \
  }
#define LOADWLDS(WP)                                                          \
  _Pragma("unroll") for (int kk=0;kk<2;++kk)                                  \
  _Pragma("unroll") for (int q=0;q<4;++q) {                                   \
    int ctg = q*16 + w;                                                       \
    const signed char* gp = (WP) + ((size_t)((kk+2)*64 + ctg)*64 + l)*16;     \
    __builtin_amdgcn_global_load_lds((gu32*)gp, (lu32*)&pLDS[w][kk][q][0], 16, 0, 0); \
  }
#define AHK(ah, hB, kf) ah = *(i32x4*)&(hB)[li*256 + ((((kf)*4)+hi) ^ (li&7))*16];
#define MFMA_ALL(hB) {                                                        \
  i32x4 ah;                                                                   \
  _Pragma("unroll") for (int kk=0;kk<2;++kk) {                                \
    AHK(ah, hB, kk)                                                           \
    _Pragma("unroll") for (int q=0;q<4;++q)                                   \
      acc[q] = MFMAI8(ah, wreg[kk*4+q], acc[q]);                              \
  }                                                                           \
  _Pragma("unroll") for (int kk=0;kk<2;++kk) {                                \
    AHK(ah, hB, kk+2)                                                         \
    _Pragma("unroll") for (int q=0;q<4;++q) {                                 \
      i32x4 b = *(i32x4*)&pLDS[w][kk][q][l*16];                               \
      acc[q] = MFMAI8(ah, b, acc[q]);                                         \
    }                                                                         \
  } }
#define LOADPV(dst, base, t_)                                                 \
  _Pragma("unroll")                                                           \
  for (int q=0;q<4;++q)                                                       \
    dst[q] = *(const f16x4*)((base) + ((size_t)(t_)*16384 + (size_t)(q*16 + w)*256 + l*4));
#define ACCZERO()                                                             \
  i32x4 acc[4];                                                               \
  _Pragma("unroll")                                                           \
  for (int q=0;q<4;++q) acc[q] = (i32x4){0,0,0,0};
#define HWRITE(hB, r, hc, hval)                                               \
  (hB)[(r)*256 + ((((hc)>>4) ^ ((r)&7))<<4) + ((hc)&15)] =                    \
      (signed char)__float2int_rn((hval)*127.0f);
#define VMW0() { asm volatile("s_waitcnt vmcnt(0)" ::: "memory");             \
                 __builtin_amdgcn_sched_barrier(0); }

  const f16* prE = pregE + (size_t)bblk*5*16384;
  const f16* prD = pregD + (size_t)bblk*25*16384;
  const int hc = w*16 + li;                    // this thread's h column
  f16x4 pvA[4];

  // one-time encoder weight load
  LOADWLDS(Whh_e_p)
  LOADWREG(Whh_e_p)
  VMW0()                          // pLDS (wave-private) + wreg retired
  __syncthreads();                // W3h + dpart init visible

  // ---------------- encoder (gate = pv + acc: bias+pos pre-folded) ---------
  for (int t=0;t<5;++t) {
    LOADPV(pvA, prE, t)           // latency hides under MFMA_ALL + TLP
    ACCZERO()
    if (t > 0) MFMA_ALL(hBuf[(t-1)&1])
#pragma unroll
    for (int i=0;i<4;++i) {
      int r = hi*4 + i;
      float gq[4];
#pragma unroll
      for (int q=0;q<4;++q)
        gq[q] = (float)pvA[q][i] + (float)acc[q][i]*SC;
      float cn = sigm(gq[1])*c_st[i] + sigm(gq[0])*tanh_(gq[2]);
      c_st[i] = cn;
      float h = sigm(gq[3])*tanh_(cn);
      HWRITE(hBuf[t&1], r, hc, h)
    }
    bar_lgkm();                   // h[t] visible
  }

  // ---------------- switch to decoder weights + constants ----------------
  LOADWLDS(Whh_d_p)               // own-wave region; enc reads finished
  LOADWREG(Whh_d_p)
  float w2r[3];
  w2r[0]=W2Wo[hc*3+0]; w2r[1]=W2Wo[hc*3+1]; w2r[2]=W2Wo[hc*3+2];
  const float b2w0 = b2Wo[0], b2w1 = b2Wo[1], b2w2 = b2Wo[2];
  float pp[4][3];
#pragma unroll
  for (int i=0;i<4;++i) {
    int r = rb + hi*4 + i;
    pp[i][0]=dec_pos[r*3+0]; pp[i][1]=dec_pos[r*3+1]; pp[i][2]=dec_pos[r*3+2];
  }
  VMW0()                          // dec pLDS writes + wreg retired

  // ---------------- decoder (1 barrier/step) ----------------
  // enc t=4 wrote hBuf[0]; dec step t reads hBuf[t&1], writes hBuf[(t+1)&1].
  for (int t=0;t<25;++t) {
    LOADPV(pvA, prD, t)
    ACCZERO()
    MFMA_ALL(hBuf[t&1])
    // per-step W3 gather from LDS (f16) — transient regs
    float w3v[4][3];
#pragma unroll
    for (int q=0;q<4;++q) {
      int gc = q*256 + hc;
      w3v[q][0] = (float)W3h[gc];
      w3v[q][1] = (float)W3h[1024+gc];
      w3v[q][2] = (float)W3h[2048+gc];
    }
    float dpar[4][3];
#pragma unroll
    for (int i=0;i<4;++i) {
      int r = hi*4 + i;
      float gq[4];
#pragma unroll
      for (int q=0;q<4;++q)
        gq[q] = (float)pvA[q][i] + (float)acc[q][i]*SC
              + pp[i][0]*w3v[q][0] + pp[i][1]*w3v[q][1] + pp[i][2]*w3v[q][2];
      float cn = sigm(gq[1])*c_st[i] + sigm(gq[0])*tanh_(gq[2]);
      c_st[i] = cn;
      float h = sigm(gq[3])*tanh_(cn);
      HWRITE(hBuf[(t+1)&1], r, hc, h)
      dpar[i][0] = h*w2r[0];
      dpar[i][1] = h*w2r[1];
      dpar[i][2] = h*w2r[2];
    }
#pragma unroll
    for (int m=1;m<16;m<<=1)
#pragma unroll
      for (int i=0;i<4;++i) {
        dpar[i][0] += __shfl_xor(dpar[i][0], m);
        dpar[i][1] += __shfl_xor(dpar[i][1], m);
        dpar[i][2] += __shfl_xor(dpar[i][2], m);
      }
    if (li==0) {
#pragma unroll
      for (int i=0;i<4;++i) {
        int r = hi*4 + i;
        atomicAdd(&dpart[t][r][0], dpar[i][0]);
        atomicAdd(&dpart[t][r][1], dpar[i][1]);
        atomicAdd(&dpart[t][r][2], dpar[i][2]);
      }
    }
    bar_lgkm();                   // h[t+1] + dpart[t] visible
#pragma unroll
    for (int i=0;i<4;++i) {
      int r = hi*4 + i;
      float p0 = pp[i][0] + b2w0 + dpart[t][r][0];
      float p1 = pp[i][1] + b2w1 + dpart[t][r][1];
      float p2 = pp[i][2] + b2w2 + dpart[t][r][2];
      float inv = frsq(p0*p0+p1*p1+p2*p2);
      pp[i][0]=p0*inv; pp[i][1]=p1*inv; pp[i][2]=p2*inv;
      if (w==0 && li==0) {
        float* o = out + (size_t)(rb+r)*75 + t*3;
        o[0]=pp[i][0]; o[1]=pp[i][1]; o[2]=pp[i][2];
      }
    }
  }
#undef LOADWREG
#undef LOADWLDS
#undef AHK
#undef MFMA_ALL
#undef LOADPV
#undef ACCZERO
#undef HWRITE
#undef VMW0
}

// ================= launch =================
extern "C" void kernel_launch(void* const* d_in, const int* in_sizes, int n_in,
                              void* d_out, int out_size, void* d_ws, size_t ws_size,
                              hipStream_t stream)
{
  const float* enc_pos = (const float*)d_in[0];
  const float* enc_sal = (const float*)d_in[1];
  const float* dec_pos = (const float*)d_in[2];
  const float* dec_sal = (const float*)d_in[3];
  const float* Wpe  = (const float*)d_in[4];
  const float* bpe  = (const float*)d_in[5];
  const float* Wse  = (const float*)d_in[6];
  const float* bse  = (const float*)d_in[7];
  const float* Wih_e= (const float*)d_in[8];
  const float* Whh_e= (const float*)d_in[9];
  const float* bih_e= (const float*)d_in[10];
  const float* bhh_e= (const float*)d_in[11];
  const float* Wih_d= (const float*)d_in[12];
  const float* Whh_d= (const float*)d_in[13];
  const float* bih_d= (const float*)d_in[14];
  const float* bhh_d= (const float*)d_in[15];
  const float* Wpd  = (const float*)d_in[16];
  const float* bpd  = (const float*)d_in[17];
  const float* Wsd  = (const float*)d_in[18];
  const float* bsd  = (const float*)d_in[19];
  const float* W2   = (const float*)d_in[20];
  const float* b2   = (const float*)d_in[21];
  const float* Wo   = (const float*)d_in[22];
  const float* bo   = (const float*)d_in[23];

  char* ws = (char*)d_ws;
  f16* pWse   = (f16*)(ws + OFF_WSE_P);
  f16* pWsd   = (f16*)(ws + OFF_WSD_P);
  f16* pWih_e = (f16*)(ws + OFF_WIHE_P);
  f16* pWih_d = (f16*)(ws + OFF_WIHD_P);
  signed char* pWhh_e = (signed char*)(ws + OFF_WHHE_P);
  signed char* pWhh_d = (signed char*)(ws + OFF_WHHD_P);
  float* W3e  = (float*)(ws + OFF_W3E);
  float* W3d  = (float*)(ws + OFF_W3D);
  float* W2WoP= (float*)(ws + OFF_W2WO);
  float* biasE= (float*)(ws + OFF_BIASE);
  float* biasD= (float*)(ws + OFF_BIASD);
  float* b2WoP= (float*)(ws + OFF_B2WO);
  f16* pregE  = (f16*)(ws + OFF_PREGE);
  f16* pregD  = (f16*)(ws + OFF_PREGD);
  float* out  = (float*)d_out;

  hipLaunchKernelGGL(k_prep, dim3(2442), dim3(256), 0, stream,
                     Wse, Wsd, Wih_e, Wih_d, Whh_e, Whh_d,
                     pWse, pWsd, pWih_e, pWih_d, pWhh_e, pWhh_d,
                     Wpe, bpe, bih_e, bhh_e, Wpd, bpd, bih_d, bhh_d,
                     W2, b2, Wo, bo,
                     W3e, W3d, biasE, biasD, W2WoP, b2WoP);
  // fused sal-projection + pre-gate GEMM: enc tiles [0,80), dec [80,480)
  hipLaunchKernelGGL(k_gemm_fused, dim3(480), dim3(256), 0, stream,
                     enc_sal, pWse, bse, pWih_e, biasE, pregE, 80, 5, enc_pos, W3e,
                     dec_sal, pWsd, bsd, pWih_d, biasD, pregD, 25);
  // recurrent kernel: resident weights, 16 waves, ~115 live regs (no spill)
  hipLaunchKernelGGL(k_rnn, dim3(64), dim3(1024), 0, stream,
                     pregE, pregD, pWhh_e, pWhh_d,
                     W3d, dec_pos, W2WoP, b2WoP, out);
}